// Round 8
// baseline (1843.084 us; speedup 1.0000x reference)
//
#include <hip/hip_runtime.h>
#include <hip/hip_fp16.h>

#define B 256
#define T 128
#define D 76
#define H 128
#define G 512   // 4H
#define H2 256  // 2H

typedef unsigned int uint32;
typedef unsigned short ushort16;
typedef _Float16 h2_t __attribute__((ext_vector_type(2)));

__device__ __forceinline__ float sigm(float x){ return 1.0f/(1.0f+__expf(-x)); }
__device__ __forceinline__ float fast_rcp(float x){ float r; asm volatile("v_rcp_f32 %0, %1" : "=v"(r) : "v"(x)); return r; }
__device__ __forceinline__ float fast_tanh(float x){ return 1.0f - 2.0f*fast_rcp(1.0f + __expf(2.0f*x)); }
__device__ __forceinline__ float bflo(uint32 u){ return __uint_as_float(u<<16); }
__device__ __forceinline__ float bfhi(uint32 u){ return __uint_as_float(u & 0xffff0000u); }
__device__ __forceinline__ ushort16 f2bf(float f){ uint32 u=__float_as_uint(f); return (ushort16)((u + 0x7fffu + ((u>>16)&1u))>>16); }
__device__ __forceinline__ float h2f_lo(uint32 u){ return __half2float(__ushort_as_half((unsigned short)(u & 0xffffu))); }
__device__ __forceinline__ float h2f_hi(uint32 u){ return __half2float(__ushort_as_half((unsigned short)(u >> 16))); }
__device__ __forceinline__ uint32 pk_f16(float a, float b){
  return (uint32)__half_as_ushort(__float2half(a)) | ((uint32)__half_as_ushort(__float2half(b))<<16);
}
__device__ __forceinline__ uint32 pk_bf16(float a, float b){
  return (uint32)f2bf(a) | ((uint32)f2bf(b)<<16);
}
__device__ __forceinline__ float dot2(uint32 w, uint32 h, float acc){
  return __builtin_amdgcn_fdot2(__builtin_bit_cast(h2_t, w), __builtin_bit_cast(h2_t, h), acc, false);
}

// ---------- fused weight transposes (9 segs) ----------
struct PrepArgs {
  const float* src[9];
  float* dst[9];
  int Gn[9]; int R[9]; int C[9];
};
__global__ __launch_bounds__(256) void prep_k(PrepArgs a){
  int seg = blockIdx.x >> 5;
  const float* s=a.src[seg]; float* d=a.dst[seg];
  int R=a.R[seg], C=a.C[seg], tot=a.Gn[seg]*R*C;
  for (int i=(blockIdx.x&31)*256+threadIdx.x; i<tot; i+=32*256){
    int g=i/(R*C); int rc=i-g*(R*C); int r=rc/C, c=rc-r*C;
    d[((size_t)g*C+c)*R + r] = s[i];
  }
}

// ---------- pack Whh (enc+dec) f16 k-pairs: wpk[phase][d][k2][j] ----------
__global__ __launch_bounds__(256) void pack_whh_k(
  const float* __restrict__ eWhh, const float* __restrict__ dWhh,
  uint32* __restrict__ wpkE, uint32* __restrict__ wpkD)
{
  int idx = blockIdx.x*256 + threadIdx.x;      // 131072 total
  int phase = idx >> 16;
  int rem = idx & 65535;
  int d = rem >> 15;
  int k2 = (rem >> 9) & 63;
  int j = rem & 511;
  const float* Wsrc = phase ? dWhh : eWhh;
  float2 wa = *(const float2*)(Wsrc + ((size_t)(d*512 + j))*128 + 2*k2);
  (phase ? wpkD : wpkE)[rem] = pk_f16(wa.x, wa.y);
}

// ---------- xg = x @ Wih^T + b, flat f16 [d][b][t][512]. shift=1 for decoder ----------
__global__ __launch_bounds__(256) void xg_k(
  const float* __restrict__ x, const float* __restrict__ WihT, const float* __restrict__ bias,
  __half* __restrict__ xgh, int shift)
{
  int d = blockIdx.x >> 11;
  int blk = blockIdx.x & 2047;
  int b = blk >> 3, t0 = (blk & 7) * 16;
  int tid = threadIdx.x;
  __shared__ __align__(16) float xs[16][D];    // 76 = 19*4, rows 304B (16B aligned)
  for (int i=tid;i<16*D;i+=256){
    int r=i/D, k=i-r*D, ts=t0+r-shift;
    xs[r][k] = (ts>=0) ? x[((size_t)b*T+ts)*D + k] : 0.f;
  }
  __syncthreads();
  const float* Wi = WihT + (size_t)d*D*G;
  float a0[16], a1[16];
  #pragma unroll
  for(int r=0;r<16;r++){a0[r]=0.f;a1[r]=0.f;}
  for (int k4=0;k4<19;k4++){
    const float* Wk = Wi + (size_t)(4*k4)*G + tid;
    float w00=Wk[0],     w01=Wk[256];
    float w10=Wk[G],     w11=Wk[G+256];
    float w20=Wk[2*G],   w21=Wk[2*G+256];
    float w30=Wk[3*G],   w31=Wk[3*G+256];
    #pragma unroll
    for(int r=0;r<16;r++){
      float4 xv = *(const float4*)&xs[r][4*k4];
      a0[r] += xv.x*w00 + xv.y*w10 + xv.z*w20 + xv.w*w30;
      a1[r] += xv.x*w01 + xv.y*w11 + xv.z*w21 + xv.w*w31;
    }
  }
  float bb0=bias[d*G+tid], bb1=bias[d*G+tid+256];
  #pragma unroll
  for(int r=0;r<16;r++){
    size_t row = (size_t)(d*B + b)*T + (t0+r);
    xgh[row*512 + tid]       = __float2half(a0[r]+bb0);
    xgh[row*512 + tid + 256] = __float2half(a1[r]+bb1);
  }
}

// ---------- recurrence: block=(dir,b) 512 thr; weights in 64 VGPRs; dot2; xg prefetch ----------
template<int ENC>
__global__ __launch_bounds__(512,2) void rec_k(
  const __half* __restrict__ xgh, const uint32* __restrict__ wpk,
  const float* __restrict__ h0, __half* __restrict__ on16,
  float* __restrict__ h_fin, float* __restrict__ h_state)
{
  int d = blockIdx.x >> 8;
  int b = blockIdx.x & 255;
  int tid = threadIdx.x;               // gate j in [0,512)
  __shared__ float gl[G];
  __shared__ __half hs_h[H];
  uint32 wreg[64];
  const uint32* wp = wpk + (size_t)d*64*512;
  #pragma unroll
  for (int k2=0;k2<64;k2++) wreg[k2] = wp[k2*512 + tid];
  if (tid < H){
    float hv = ENC ? 0.f : h0[(size_t)d*B*H + (size_t)b*H + tid];
    hs_h[tid] = __float2half(hv);
  }
  float creg = 0.f, hlast = 0.f;
  const __half* xrow = xgh + (size_t)(d*B + b)*T*512;
  // prefetch t=0
  int te0 = ENC ? (d ? (T-1) : 0) : 0;
  __half xr_next = xrow[(size_t)te0*512 + tid];
  __syncthreads();
  for (int t=0;t<T;t++){
    int te = ENC ? (d ? (T-1-t) : t) : t;
    __half xr = xr_next;
    if (t+1 < T){
      int tn = ENC ? (d ? (T-2-t) : (t+1)) : (t+1);
      xr_next = xrow[(size_t)tn*512 + tid];      // issued now, used next step
    }
    const uint32* h32 = (const uint32*)hs_h;
    float acc0 = 0.f, acc1 = 0.f;
    #pragma unroll
    for (int k2=0;k2<64;k2+=2){
      acc0 = dot2(wreg[k2],   h32[k2],   acc0);
      acc1 = dot2(wreg[k2+1], h32[k2+1], acc1);
    }
    gl[tid] = acc0 + acc1 + __half2float(xr);
    __syncthreads();
    if (tid < H){
      float ii=sigm(gl[tid]), ff=sigm(gl[128+tid]);
      float gg=fast_tanh(gl[256+tid]), oo=sigm(gl[384+tid]);
      creg = ff*creg + ii*gg;
      float hv = oo*fast_tanh(creg);
      hlast = hv;
      hs_h[tid] = __float2half(hv);
      if (ENC) on16[((size_t)b*T + te)*H2 + d*H + tid] = __float2half(hv);
      else     h_state[(size_t)(t+1)*2*B*H + (size_t)d*B*H + (size_t)b*H + tid] = hv;
    }
    __syncthreads();
  }
  if (ENC && tid < H) h_fin[(size_t)d*B*H + (size_t)b*H + tid] = hlast;
}

// ---------- z = mu + eps*exp(0.5 lv) -> h_state[0] ----------
__global__ __launch_bounds__(128) void z_k(
  const float* __restrict__ h_fin, const float* __restrict__ WzmuT, const float* __restrict__ bzmu,
  const float* __restrict__ WzlvT, const float* __restrict__ bzlv, const float* __restrict__ eps_z,
  float* __restrict__ h_state0)
{
  __shared__ float hr[H];
  int d = blockIdx.x >> 8; int b = blockIdx.x & 255;
  int j = threadIdx.x;
  hr[j] = h_fin[(size_t)d*B*H + (size_t)b*H + j];
  __syncthreads();
  float mu=bzmu[j], lv=bzlv[j];
  #pragma unroll 4
  for(int k=0;k<H;k++){ float hv=hr[k]; mu+=hv*WzmuT[k*H+j]; lv+=hv*WzlvT[k*H+j]; }
  size_t idx=(size_t)d*B*H + (size_t)b*H + j;
  h_state0[idx] = mu + eps_z[idx]*__expf(0.5f*lv);
}

// ---------- fused on_s (bf16) + eb = exp(2*(on_s@W2T+b2)) f32 ----------
__global__ __launch_bounds__(256) void onsw2v_k(
  const uint32* __restrict__ on32, const float* __restrict__ WomuT, const float* __restrict__ bomu,
  const float* __restrict__ WolvT, const float* __restrict__ bolv, const float* __restrict__ eps_on,
  const float* __restrict__ W2T, const float* __restrict__ b2,
  ushort16* __restrict__ onsb, float* __restrict__ ebg)
{
  __shared__ __align__(16) float tile[16][H2];
  __shared__ __align__(16) float t2[16][H2];
  size_t row0=(size_t)blockIdx.x*16;
  int tid=threadIdx.x;
  for(int i=tid;i<16*128;i+=256){
    uint32 u = on32[row0*128 + i];
    int r=i>>7, c2=i&127;
    tile[r][2*c2]=h2f_lo(u); tile[r][2*c2+1]=h2f_hi(u);
  }
  __syncthreads();
  float am[16], al[16];
  #pragma unroll
  for(int r=0;r<16;r++){am[r]=0.f;al[r]=0.f;}
  for(int k4=0;k4<64;k4++){
    int k=4*k4;
    float wm0=WomuT[(size_t)k*H2+tid],     wm1=WomuT[(size_t)(k+1)*H2+tid];
    float wm2=WomuT[(size_t)(k+2)*H2+tid], wm3=WomuT[(size_t)(k+3)*H2+tid];
    float wl0=WolvT[(size_t)k*H2+tid],     wl1=WolvT[(size_t)(k+1)*H2+tid];
    float wl2=WolvT[(size_t)(k+2)*H2+tid], wl3=WolvT[(size_t)(k+3)*H2+tid];
    #pragma unroll
    for(int r=0;r<16;r++){
      float4 v = *(const float4*)&tile[r][k];
      am[r] += v.x*wm0 + v.y*wm1 + v.z*wm2 + v.w*wm3;
      al[r] += v.x*wl0 + v.y*wl1 + v.z*wl2 + v.w*wl3;
    }
  }
  float bm=bomu[tid], bl=bolv[tid];
  #pragma unroll
  for(int r=0;r<16;r++){
    size_t row=row0+r;
    float v = am[r]+bm + eps_on[row*H2+tid]*__expf(0.5f*(al[r]+bl));
    t2[r][tid]=v;
    onsb[row*H2+tid]=f2bf(v);
  }
  __syncthreads();
  float ac[16];
  #pragma unroll
  for(int r=0;r<16;r++) ac[r]=0.f;
  for(int k4=0;k4<64;k4++){
    int k=4*k4;
    float w0=W2T[(size_t)k*H2+tid],     w1=W2T[(size_t)(k+1)*H2+tid];
    float w2=W2T[(size_t)(k+2)*H2+tid], w3=W2T[(size_t)(k+3)*H2+tid];
    #pragma unroll
    for(int r=0;r<16;r++){
      float4 v = *(const float4*)&t2[r][k];
      ac[r] += v.x*w0 + v.y*w1 + v.z*w2 + v.w*w3;
    }
  }
  float bb=b2[tid];
  #pragma unroll
  for(int r=0;r<16;r++) ebg[(row0+r)*H2+tid]=__expf(2.0f*(ac[r]+bb));
}

// ---------- eq = exp(2*(concat(h0,h1)@W1T+b1)), all (b,t), f32 out ----------
__global__ __launch_bounds__(256) void qp_all_k(
  const float* __restrict__ h_state, const float* __restrict__ W1T, const float* __restrict__ b1,
  float* __restrict__ eqg)
{
  int m0 = blockIdx.x*16; int b = m0>>7; int t0 = m0&127;
  __shared__ __align__(16) float tile[16][H2];
  int tid=threadIdx.x;
  for (int i=tid;i<16*H2;i+=256){
    int r=i>>8, k=i&255; int dd=k>>7, kk=k&127;
    tile[r][k] = h_state[(size_t)(t0+r)*2*B*H + (size_t)dd*B*H + (size_t)b*H + kk];
  }
  __syncthreads();
  float ac[16];
  #pragma unroll
  for(int r=0;r<16;r++) ac[r]=0.f;
  for(int k4=0;k4<64;k4++){
    int k=4*k4;
    float w0=W1T[(size_t)k*H2+tid],     w1=W1T[(size_t)(k+1)*H2+tid];
    float w2=W1T[(size_t)(k+2)*H2+tid], w3=W1T[(size_t)(k+3)*H2+tid];
    #pragma unroll
    for(int r=0;r<16;r++){
      float4 v = *(const float4*)&tile[r][k];
      ac[r] += v.x*w0 + v.y*w1 + v.z*w2 + v.w*w3;
    }
  }
  float bb=b1[tid];
  #pragma unroll
  for(int r=0;r<16;r++) eqg[(size_t)(m0+r)*H2+tid]=__expf(2.0f*(ac[r]+bb));
}

// ---------- attention: block=(b,t-half); V + eb in registers; TQ=2; 3 syncs/pair ----------
__global__ __launch_bounds__(512,4) void attn_k(
  const float* __restrict__ eqg, const float* __restrict__ ebg, const uint32* __restrict__ ons32,
  const float* __restrict__ att_v, float* __restrict__ ctx)
{
  int b  = blockIdx.x >> 1;
  int t0 = (blockIdx.x & 1) * 64;
  int tid = threadIdx.x;
  int jq = tid & 15, ttb = tid >> 4;          // score mapping
  int jp = tid & 127, q = tid >> 7;           // PV mapping
  __shared__ __align__(16) float eqs[2][2*H2]; // double-buffered, 4 KB
  __shared__ __align__(16) float sc[2][T];
  __shared__ float2 pv2[2][4][128];
  __shared__ float wsum4[4];
  __shared__ float wvs[H2];
  // V quarter-column in registers (t-invariant): rows q*32..q*32+31, col-pair jp
  uint32 vreg[32];
  {
    const uint32* vsg = ons32 + (size_t)b*T*128 + jp;
    #pragma unroll
    for (int r=0;r<32;r++) vreg[r] = vsg[(size_t)(q*32+r)*128];
  }
  // eb: 4 tt rows x 16 j, bf16-packed; t-invariant
  uint32 ebp01[16], ebp23[16];
  float vsum_mine = 0.f;
  {
    const float* ebb = ebg + (size_t)b*T*H2;
    #pragma unroll
    for (int ii=0;ii<16;ii++){
      int j = jq + 16*ii;
      float e0 = ebb[(size_t)(ttb    )*H2 + j];
      float e1 = ebb[(size_t)(ttb+32 )*H2 + j];
      float e2 = ebb[(size_t)(ttb+64 )*H2 + j];
      float e3 = ebb[(size_t)(ttb+96 )*H2 + j];
      ebp01[ii] = pk_bf16(e0, e1);
      ebp23[ii] = pk_bf16(e2, e3);
      vsum_mine += att_v[j];
    }
  }
  if (tid < H2) wvs[tid] = -2.0f*att_v[tid];
  // stage first query pair
  if (tid < 128) ((float4*)eqs[0])[tid] = ((const float4*)(eqg + ((size_t)b*T + t0)*H2))[tid];
  __syncthreads();
  int buf = 0;
  for (int tq=0; tq<64; tq+=2){
    // prefetch next pair into the other buffer (no hazard: nobody reads it yet)
    if (tq+2 < 64 && tid < 128)
      ((float4*)eqs[buf^1])[tid] = ((const float4*)(eqg + ((size_t)b*T + t0+tq+2)*H2))[tid];
    const float* eq0 = eqs[buf];
    const float* eq1 = eqs[buf] + H2;
    float a00=vsum_mine,a01=vsum_mine,a02=vsum_mine,a03=vsum_mine;
    float a10=vsum_mine,a11=vsum_mine,a12=vsum_mine,a13=vsum_mine;
    #pragma unroll
    for (int ii=0; ii<16; ii++){
      float e0=bflo(ebp01[ii]), e1=bfhi(ebp01[ii]);
      float e2=bflo(ebp23[ii]), e3=bfhi(ebp23[ii]);
      float q0=eq0[jq+16*ii], q1=eq1[jq+16*ii];
      float w=wvs[jq+16*ii];
      a00 = fmaf(w, fast_rcp(fmaf(e0,q0,1.f)), a00);
      a01 = fmaf(w, fast_rcp(fmaf(e1,q0,1.f)), a01);
      a02 = fmaf(w, fast_rcp(fmaf(e2,q0,1.f)), a02);
      a03 = fmaf(w, fast_rcp(fmaf(e3,q0,1.f)), a03);
      a10 = fmaf(w, fast_rcp(fmaf(e0,q1,1.f)), a10);
      a11 = fmaf(w, fast_rcp(fmaf(e1,q1,1.f)), a11);
      a12 = fmaf(w, fast_rcp(fmaf(e2,q1,1.f)), a12);
      a13 = fmaf(w, fast_rcp(fmaf(e3,q1,1.f)), a13);
    }
    #pragma unroll
    for (int off=1; off<16; off<<=1){
      a00 += __shfl_xor(a00,off); a01 += __shfl_xor(a01,off);
      a02 += __shfl_xor(a02,off); a03 += __shfl_xor(a03,off);
      a10 += __shfl_xor(a10,off); a11 += __shfl_xor(a11,off);
      a12 += __shfl_xor(a12,off); a13 += __shfl_xor(a13,off);
    }
    if (jq==0){
      sc[0][ttb]=__expf(a00); sc[0][ttb+32]=__expf(a01); sc[0][ttb+64]=__expf(a02); sc[0][ttb+96]=__expf(a03);
      sc[1][ttb]=__expf(a10); sc[1][ttb+32]=__expf(a11); sc[1][ttb+64]=__expf(a12); sc[1][ttb+96]=__expf(a13);
    }
    __syncthreads();                         // A: sc ready
    if (tid < 256){
      int row = tid>>7;
      float e = sc[row][tid&127];
      #pragma unroll
      for (int off=1; off<64; off<<=1) e += __shfl_xor(e,off);
      if ((tid&63)==0) wsum4[tid>>6]=e;
    }
    float p00=0.f,p01=0.f,p10=0.f,p11=0.f;
    #pragma unroll
    for (int k=0;k<8;k++){
      float4 s0 = ((const float4*)sc[0])[q*8+k];
      float4 s1 = ((const float4*)sc[1])[q*8+k];
      uint32 u0 = vreg[4*k], u1 = vreg[4*k+1], u2 = vreg[4*k+2], u3 = vreg[4*k+3];
      float lo0=bflo(u0),hi0=bfhi(u0),lo1=bflo(u1),hi1=bfhi(u1);
      float lo2=bflo(u2),hi2=bfhi(u2),lo3=bflo(u3),hi3=bfhi(u3);
      p00 += s0.x*lo0 + s0.y*lo1 + s0.z*lo2 + s0.w*lo3;
      p01 += s0.x*hi0 + s0.y*hi1 + s0.z*hi2 + s0.w*hi3;
      p10 += s1.x*lo0 + s1.y*lo1 + s1.z*lo2 + s1.w*lo3;
      p11 += s1.x*hi0 + s1.y*hi1 + s1.z*hi2 + s1.w*hi3;
    }
    pv2[0][q][jp] = make_float2(p00,p01);
    pv2[1][q][jp] = make_float2(p10,p11);
    __syncthreads();                         // B: pv2 + wsum4 ready
    {
      int row = tid>>8, jj = tid&255;
      float2 r0=pv2[row][0][jj>>1], r1=pv2[row][1][jj>>1], r2=pv2[row][2][jj>>1], r3=pv2[row][3][jj>>1];
      float r = (jj&1) ? (r0.y+r1.y+r2.y+r3.y) : (r0.x+r1.x+r2.x+r3.x);
      float tot = row ? (wsum4[2]+wsum4[3]) : (wsum4[0]+wsum4[1]);
      ctx[((size_t)b*T + t0+tq+row)*H2 + jj] = r * fast_rcp(tot*128.0f);
    }
    __syncthreads();                         // C: ctx-write done before sc/pv2 reuse
    buf ^= 1;
  }
}

// ---------- output projection, all (b,t) ----------
__global__ __launch_bounds__(256) void outproj_k(
  const float* __restrict__ h_state, const float* __restrict__ ctx,
  const float* __restrict__ WoutT, const float* __restrict__ bout, float* __restrict__ out)
{
  int m0 = blockIdx.x*16; int b = m0>>7; int t0 = m0&127;
  __shared__ __align__(16) float rb[16][G];
  int tid=threadIdx.x;
  for (int i=tid;i<16*G;i+=256){
    int r=i>>9, c=i&511;
    int t = t0+r;
    float v;
    if (c<H)       v = h_state[(size_t)(t+1)*2*B*H + (size_t)b*H + c];
    else if (c<H2) v = h_state[(size_t)(t+1)*2*B*H + (size_t)B*H + (size_t)b*H + (c-H)];
    else           v = ctx[((size_t)(m0+r))*H2 + (c-H2)];
    rb[r][c]=v;
  }
  __syncthreads();
  for (int o=tid;o<16*D;o+=256){
    int r=o/D, j=o-r*D;
    float acc=bout[j];
    for (int k4=0;k4<128;k4++){
      int k=4*k4;
      float4 rv = *(const float4*)&rb[r][k];
      acc += rv.x*WoutT[(size_t)k*D+j]     + rv.y*WoutT[(size_t)(k+1)*D+j]
           + rv.z*WoutT[(size_t)(k+2)*D+j] + rv.w*WoutT[(size_t)(k+3)*D+j];
    }
    out[((size_t)(m0+r))*D + j]=acc;
  }
}

extern "C" void kernel_launch(void* const* d_in, const int* in_sizes, int n_in,
                              void* d_out, int out_size, void* d_ws, size_t ws_size,
                              hipStream_t stream) {
  const float* x      =(const float*)d_in[0];
  const float* eps_z  =(const float*)d_in[1];
  const float* eps_on =(const float*)d_in[2];
  const float* enc_Wih=(const float*)d_in[3];
  const float* enc_Whh=(const float*)d_in[4];
  const float* enc_b  =(const float*)d_in[5];
  const float* dec_Wih=(const float*)d_in[6];
  const float* dec_Whh=(const float*)d_in[7];
  const float* dec_b  =(const float*)d_in[8];
  const float* Wzmu=(const float*)d_in[9];  const float* bzmu=(const float*)d_in[10];
  const float* Wzlv=(const float*)d_in[11]; const float* bzlv=(const float*)d_in[12];
  const float* Womu=(const float*)d_in[13]; const float* bomu=(const float*)d_in[14];
  const float* Wolv=(const float*)d_in[15]; const float* bolv=(const float*)d_in[16];
  const float* att_v=(const float*)d_in[17];
  const float* att_W1=(const float*)d_in[18]; const float* att_b1=(const float*)d_in[19];
  const float* att_W2=(const float*)d_in[20]; const float* att_b2=(const float*)d_in[21];
  const float* Wout=(const float*)d_in[22];  const float* bout=(const float*)d_in[23];
  float* out=(float*)d_out;
  float* ws=(float*)d_ws;
  (void)ws_size; (void)n_in; (void)in_sizes; (void)out_size;

  size_t o=0;
  float* encWihT=ws+o; o+=2*D*G;
  float* decWihT=ws+o; o+=2*D*G;
  float* WzmuT=ws+o; o+=H*H;
  float* WzlvT=ws+o; o+=H*H;
  float* WomuT=ws+o; o+=H2*H2;
  float* WolvT=ws+o; o+=H2*H2;
  float* W1T  =ws+o; o+=H2*H2;
  float* W2T  =ws+o; o+=H2*H2;
  float* WoutT=ws+o; o+=G*D;
  uint32* wpkE=(uint32*)(ws+o); o+=65536;        // [d][k2][j] f16-pairs
  uint32* wpkD=(uint32*)(ws+o); o+=65536;
  float* h_fin=ws+o; o+=2*B*H;
  __half* on16=(__half*)(ws+o); o+=(size_t)B*T*H2/2;
  float* h_state=ws+o; o+=(size_t)(T+1)*2*B*H;
  float* Abase=ws+o; o+=16777216;                // 64MB: xghE -> xghD -> {eqg 32MB | ctx 32MB}
  float* Cbase=ws+o; o+=12582912;                // 48MB: onsb 16MB + ebg 32MB

  __half* xgh = (__half*)Abase;
  float* eqg  = Abase;
  float* ctx  = Abase + 8388608;
  ushort16* onsb = (ushort16*)Cbase;
  float* ebg  = Cbase + 4194304;

  PrepArgs pa;
  const float* srcs[9]={enc_Wih,dec_Wih,Wzmu,Wzlv,Womu,Wolv,att_W1,att_W2,Wout};
  float* dsts[9]={encWihT,decWihT,WzmuT,WzlvT,WomuT,WolvT,W1T,W2T,WoutT};
  int Gns[9]={2,2,1,1,1,1,1,1,1};
  int Rs[9]={G,G,H,H,H2,H2,H2,H2,D};
  int Cs[9]={D,D,H,H,H2,H2,H2,H2,G};
  for(int i=0;i<9;i++){pa.src[i]=srcs[i];pa.dst[i]=dsts[i];pa.Gn[i]=Gns[i];pa.R[i]=Rs[i];pa.C[i]=Cs[i];}
  prep_k<<<288,256,0,stream>>>(pa);
  pack_whh_k<<<512,256,0,stream>>>(enc_Whh, dec_Whh, wpkE, wpkD);

  // encoder phase
  xg_k<<<4096,256,0,stream>>>(x, encWihT, enc_b, xgh, 0);
  rec_k<1><<<512,512,0,stream>>>(xgh, wpkE, nullptr, on16, h_fin, nullptr);
  z_k<<<512,128,0,stream>>>(h_fin, WzmuT,bzmu,WzlvT,bzlv,eps_z, h_state);
  onsw2v_k<<<2048,256,0,stream>>>((const uint32*)on16,WomuT,bomu,WolvT,bolv,eps_on,W2T,att_b2,onsb,ebg);

  // decoder phase (xg reuses region A)
  xg_k<<<4096,256,0,stream>>>(x, decWihT, dec_b, xgh, 1);
  rec_k<0><<<512,512,0,stream>>>(xgh, wpkD, h_state, nullptr, nullptr, h_state);

  qp_all_k<<<2048,256,0,stream>>>(h_state, W1T, att_b1, eqg);
  attn_k<<<512,512,0,stream>>>(eqg, ebg, (const uint32*)onsb, att_v, ctx);
  outproj_k<<<2048,256,0,stream>>>(h_state, ctx, WoutT, bout, out);
}

// Round 9
// 1154.060 us; speedup vs baseline: 1.5970x; 1.5970x over previous
//
#include <hip/hip_runtime.h>
#include <hip/hip_fp16.h>

#define B 256
#define T 128
#define D 76
#define H 128
#define G 512   // 4H
#define H2 256  // 2H

typedef unsigned int uint32;
typedef unsigned short ushort16;
typedef _Float16 h2_t __attribute__((ext_vector_type(2)));

__device__ __forceinline__ float sigm(float x){ return 1.0f/(1.0f+__expf(-x)); }
__device__ __forceinline__ float fast_rcp(float x){ float r; asm volatile("v_rcp_f32 %0, %1" : "=v"(r) : "v"(x)); return r; }
__device__ __forceinline__ float fast_tanh(float x){ return 1.0f - 2.0f*fast_rcp(1.0f + __expf(2.0f*x)); }
__device__ __forceinline__ float bflo(uint32 u){ return __uint_as_float(u<<16); }
__device__ __forceinline__ float bfhi(uint32 u){ return __uint_as_float(u & 0xffff0000u); }
__device__ __forceinline__ ushort16 f2bf(float f){ uint32 u=__float_as_uint(f); return (ushort16)((u + 0x7fffu + ((u>>16)&1u))>>16); }
__device__ __forceinline__ float h2f_lo(uint32 u){ return __half2float(__ushort_as_half((unsigned short)(u & 0xffffu))); }
__device__ __forceinline__ float h2f_hi(uint32 u){ return __half2float(__ushort_as_half((unsigned short)(u >> 16))); }
__device__ __forceinline__ uint32 pk_f16(float a, float b){
  return (uint32)__half_as_ushort(__float2half(a)) | ((uint32)__half_as_ushort(__float2half(b))<<16);
}
__device__ __forceinline__ uint32 pk_bf16(float a, float b){
  return (uint32)f2bf(a) | ((uint32)f2bf(b)<<16);
}
__device__ __forceinline__ float dot2(uint32 w, uint32 h, float acc){
  return __builtin_amdgcn_fdot2(__builtin_bit_cast(h2_t, w), __builtin_bit_cast(h2_t, h), acc, false);
}

// ---------- fused weight transposes (9 segs) ----------
struct PrepArgs {
  const float* src[9];
  float* dst[9];
  int Gn[9]; int R[9]; int C[9];
};
__global__ __launch_bounds__(256) void prep_k(PrepArgs a){
  int seg = blockIdx.x >> 5;
  const float* s=a.src[seg]; float* d=a.dst[seg];
  int R=a.R[seg], C=a.C[seg], tot=a.Gn[seg]*R*C;
  for (int i=(blockIdx.x&31)*256+threadIdx.x; i<tot; i+=32*256){
    int g=i/(R*C); int rc=i-g*(R*C); int r=rc/C, c=rc-r*C;
    d[((size_t)g*C+c)*R + r] = s[i];
  }
}

// ---------- pack Whh (enc+dec) f16 k-pairs: wpk[phase][d][k2][j] ----------
__global__ __launch_bounds__(256) void pack_whh_k(
  const float* __restrict__ eWhh, const float* __restrict__ dWhh,
  uint32* __restrict__ wpkE, uint32* __restrict__ wpkD)
{
  int idx = blockIdx.x*256 + threadIdx.x;      // 131072 total
  int phase = idx >> 16;
  int rem = idx & 65535;
  int d = rem >> 15;
  int k2 = (rem >> 9) & 63;
  int j = rem & 511;
  const float* Wsrc = phase ? dWhh : eWhh;
  float2 wa = *(const float2*)(Wsrc + ((size_t)(d*512 + j))*128 + 2*k2);
  (phase ? wpkD : wpkE)[rem] = pk_f16(wa.x, wa.y);
}

// ---------- xg = x @ Wih^T + b, flat f16 [d][b][t][512]. shift=1 for decoder ----------
__global__ __launch_bounds__(256) void xg_k(
  const float* __restrict__ x, const float* __restrict__ WihT, const float* __restrict__ bias,
  __half* __restrict__ xgh, int shift)
{
  int d = blockIdx.x >> 11;
  int blk = blockIdx.x & 2047;
  int b = blk >> 3, t0 = (blk & 7) * 16;
  int tid = threadIdx.x;
  __shared__ __align__(16) float xs[16][D];
  for (int i=tid;i<16*D;i+=256){
    int r=i/D, k=i-r*D, ts=t0+r-shift;
    xs[r][k] = (ts>=0) ? x[((size_t)b*T+ts)*D + k] : 0.f;
  }
  __syncthreads();
  const float* Wi = WihT + (size_t)d*D*G;
  float a0[16], a1[16];
  #pragma unroll
  for(int r=0;r<16;r++){a0[r]=0.f;a1[r]=0.f;}
  for (int k4=0;k4<19;k4++){
    const float* Wk = Wi + (size_t)(4*k4)*G + tid;
    float w00=Wk[0],     w01=Wk[256];
    float w10=Wk[G],     w11=Wk[G+256];
    float w20=Wk[2*G],   w21=Wk[2*G+256];
    float w30=Wk[3*G],   w31=Wk[3*G+256];
    #pragma unroll
    for(int r=0;r<16;r++){
      float4 xv = *(const float4*)&xs[r][4*k4];
      a0[r] += xv.x*w00 + xv.y*w10 + xv.z*w20 + xv.w*w30;
      a1[r] += xv.x*w01 + xv.y*w11 + xv.z*w21 + xv.w*w31;
    }
  }
  float bb0=bias[d*G+tid], bb1=bias[d*G+tid+256];
  #pragma unroll
  for(int r=0;r<16;r++){
    size_t row = (size_t)(d*B + b)*T + (t0+r);
    xgh[row*512 + tid]       = __float2half(a0[r]+bb0);
    xgh[row*512 + tid + 256] = __float2half(a1[r]+bb1);
  }
}

// ---------- recurrence: block=(dir,b) 512 thr; weights in 64 VGPRs; dot2; xg prefetch ----------
template<int ENC>
__global__ __launch_bounds__(512,2) void rec_k(
  const __half* __restrict__ xgh, const uint32* __restrict__ wpk,
  const float* __restrict__ h0, __half* __restrict__ on16,
  float* __restrict__ h_fin, float* __restrict__ h_state)
{
  int d = blockIdx.x >> 8;
  int b = blockIdx.x & 255;
  int tid = threadIdx.x;               // gate j in [0,512)
  __shared__ float gl[G];
  __shared__ __half hs_h[H];
  uint32 wreg[64];
  const uint32* wp = wpk + (size_t)d*64*512;
  #pragma unroll
  for (int k2=0;k2<64;k2++) wreg[k2] = wp[k2*512 + tid];
  if (tid < H){
    float hv = ENC ? 0.f : h0[(size_t)d*B*H + (size_t)b*H + tid];
    hs_h[tid] = __float2half(hv);
  }
  float creg = 0.f, hlast = 0.f;
  const __half* xrow = xgh + (size_t)(d*B + b)*T*512;
  int te0 = ENC ? (d ? (T-1) : 0) : 0;
  __half xr_next = xrow[(size_t)te0*512 + tid];
  __syncthreads();
  for (int t=0;t<T;t++){
    int te = ENC ? (d ? (T-1-t) : t) : t;
    __half xr = xr_next;
    if (t+1 < T){
      int tn = ENC ? (d ? (T-2-t) : (t+1)) : (t+1);
      xr_next = xrow[(size_t)tn*512 + tid];
    }
    const uint32* h32 = (const uint32*)hs_h;
    float acc0 = 0.f, acc1 = 0.f;
    #pragma unroll
    for (int k2=0;k2<64;k2+=2){
      acc0 = dot2(wreg[k2],   h32[k2],   acc0);
      acc1 = dot2(wreg[k2+1], h32[k2+1], acc1);
    }
    gl[tid] = acc0 + acc1 + __half2float(xr);
    __syncthreads();
    if (tid < H){
      float ii=sigm(gl[tid]), ff=sigm(gl[128+tid]);
      float gg=fast_tanh(gl[256+tid]), oo=sigm(gl[384+tid]);
      creg = ff*creg + ii*gg;
      float hv = oo*fast_tanh(creg);
      hlast = hv;
      hs_h[tid] = __float2half(hv);
      if (ENC) on16[((size_t)b*T + te)*H2 + d*H + tid] = __float2half(hv);
      else     h_state[(size_t)(t+1)*2*B*H + (size_t)d*B*H + (size_t)b*H + tid] = hv;
    }
    __syncthreads();
  }
  if (ENC && tid < H) h_fin[(size_t)d*B*H + (size_t)b*H + tid] = hlast;
}

// ---------- z = mu + eps*exp(0.5 lv) -> h_state[0] ----------
__global__ __launch_bounds__(128) void z_k(
  const float* __restrict__ h_fin, const float* __restrict__ WzmuT, const float* __restrict__ bzmu,
  const float* __restrict__ WzlvT, const float* __restrict__ bzlv, const float* __restrict__ eps_z,
  float* __restrict__ h_state0)
{
  __shared__ float hr[H];
  int d = blockIdx.x >> 8; int b = blockIdx.x & 255;
  int j = threadIdx.x;
  hr[j] = h_fin[(size_t)d*B*H + (size_t)b*H + j];
  __syncthreads();
  float mu=bzmu[j], lv=bzlv[j];
  #pragma unroll 4
  for(int k=0;k<H;k++){ float hv=hr[k]; mu+=hv*WzmuT[k*H+j]; lv+=hv*WzlvT[k*H+j]; }
  size_t idx=(size_t)d*B*H + (size_t)b*H + j;
  h_state0[idx] = mu + eps_z[idx]*__expf(0.5f*lv);
}

// ---------- fused on_s -> on_sT (f16 t-pairs, for PV) + eb = exp(2*(on_s@W2T+b2)) ----------
__global__ __launch_bounds__(256) void onsw2v_k(
  const uint32* __restrict__ on32, const float* __restrict__ WomuT, const float* __restrict__ bomu,
  const float* __restrict__ WolvT, const float* __restrict__ bolv, const float* __restrict__ eps_on,
  const float* __restrict__ W2T, const float* __restrict__ b2,
  uint32* __restrict__ onsT, float* __restrict__ ebg)
{
  __shared__ __align__(16) float tile[16][H2];
  __shared__ __align__(16) float t2[16][H2];
  size_t row0=(size_t)blockIdx.x*16;
  int b = (int)(row0 >> 7), t0 = (int)(row0 & 127);
  int tid=threadIdx.x;
  for(int i=tid;i<16*128;i+=256){
    uint32 u = on32[row0*128 + i];
    int r=i>>7, c2=i&127;
    tile[r][2*c2]=h2f_lo(u); tile[r][2*c2+1]=h2f_hi(u);
  }
  __syncthreads();
  float am[16], al[16];
  #pragma unroll
  for(int r=0;r<16;r++){am[r]=0.f;al[r]=0.f;}
  for(int k4=0;k4<64;k4++){
    int k=4*k4;
    float wm0=WomuT[(size_t)k*H2+tid],     wm1=WomuT[(size_t)(k+1)*H2+tid];
    float wm2=WomuT[(size_t)(k+2)*H2+tid], wm3=WomuT[(size_t)(k+3)*H2+tid];
    float wl0=WolvT[(size_t)k*H2+tid],     wl1=WolvT[(size_t)(k+1)*H2+tid];
    float wl2=WolvT[(size_t)(k+2)*H2+tid], wl3=WolvT[(size_t)(k+3)*H2+tid];
    #pragma unroll
    for(int r=0;r<16;r++){
      float4 v = *(const float4*)&tile[r][k];
      am[r] += v.x*wm0 + v.y*wm1 + v.z*wm2 + v.w*wm3;
      al[r] += v.x*wl0 + v.y*wl1 + v.z*wl2 + v.w*wl3;
    }
  }
  float bm=bomu[tid], bl=bolv[tid];
  #pragma unroll
  for(int r=0;r<16;r++){
    size_t row=row0+r;
    float v = am[r]+bm + eps_on[row*H2+tid]*__expf(0.5f*(al[r]+bl));
    t2[r][tid]=v;
  }
  __syncthreads();
  // on_s^T f16 t-pairs: onsT[(b*256 + j)*64 + t/2]
  #pragma unroll
  for(int rr=0;rr<8;rr++)
    onsT[((size_t)b*H2 + tid)*64 + (t0>>1) + rr] = pk_f16(t2[2*rr][tid], t2[2*rr+1][tid]);
  float ac[16];
  #pragma unroll
  for(int r=0;r<16;r++) ac[r]=0.f;
  for(int k4=0;k4<64;k4++){
    int k=4*k4;
    float w0=W2T[(size_t)k*H2+tid],     w1=W2T[(size_t)(k+1)*H2+tid];
    float w2=W2T[(size_t)(k+2)*H2+tid], w3=W2T[(size_t)(k+3)*H2+tid];
    #pragma unroll
    for(int r=0;r<16;r++){
      float4 v = *(const float4*)&t2[r][k];
      ac[r] += v.x*w0 + v.y*w1 + v.z*w2 + v.w*w3;
    }
  }
  float bb=b2[tid];
  #pragma unroll
  for(int r=0;r<16;r++) ebg[(row0+r)*H2+tid]=__expf(2.0f*(ac[r]+bb));
}

// ---------- eq = exp(2*(concat(h0,h1)@W1T+b1)), all (b,t), f32 out ----------
__global__ __launch_bounds__(256) void qp_all_k(
  const float* __restrict__ h_state, const float* __restrict__ W1T, const float* __restrict__ b1,
  float* __restrict__ eqg)
{
  int m0 = blockIdx.x*16; int b = m0>>7; int t0 = m0&127;
  __shared__ __align__(16) float tile[16][H2];
  int tid=threadIdx.x;
  for (int i=tid;i<16*H2;i+=256){
    int r=i>>8, k=i&255; int dd=k>>7, kk=k&127;
    tile[r][k] = h_state[(size_t)(t0+r)*2*B*H + (size_t)dd*B*H + (size_t)b*H + kk];
  }
  __syncthreads();
  float ac[16];
  #pragma unroll
  for(int r=0;r<16;r++) ac[r]=0.f;
  for(int k4=0;k4<64;k4++){
    int k=4*k4;
    float w0=W1T[(size_t)k*H2+tid],     w1=W1T[(size_t)(k+1)*H2+tid];
    float w2=W1T[(size_t)(k+2)*H2+tid], w3=W1T[(size_t)(k+3)*H2+tid];
    #pragma unroll
    for(int r=0;r<16;r++){
      float4 v = *(const float4*)&tile[r][k];
      ac[r] += v.x*w0 + v.y*w1 + v.z*w2 + v.w*w3;
    }
  }
  float bb=b1[tid];
  #pragma unroll
  for(int r=0;r<16;r++) eqg[(size_t)(m0+r)*H2+tid]=__expf(2.0f*(ac[r]+bb));
}

// ---------- scores: block=(b,t-half), TQ=2, eb in 32 regs; writes normalized f16 weights ----------
// NO V here -> tiny LDS -> 2 blocks/CU. 2 barriers per query pair (scl/wsum double-buffered).
__global__ __launch_bounds__(512,2) void score_k(
  const float* __restrict__ eqg, const float* __restrict__ ebg,
  const float* __restrict__ att_v, uint32* __restrict__ sc16)
{
  int b  = blockIdx.x >> 1;
  int t0 = (blockIdx.x & 1) * 64;
  int tid = threadIdx.x;
  int jq = tid & 15, ttb = tid >> 4;
  __shared__ __align__(16) float eqs[2][2*H2];
  __shared__ __align__(16) float scl[2][2][T];
  __shared__ float wsum4[2][4];
  __shared__ float wvs[H2];
  uint32 ebp01[16], ebp23[16];
  float vsum_mine = 0.f;
  {
    const float* ebb = ebg + (size_t)b*T*H2;
    #pragma unroll
    for (int ii=0;ii<16;ii++){
      int j = jq + 16*ii;
      ebp01[ii] = pk_bf16(ebb[(size_t)(ttb    )*H2 + j], ebb[(size_t)(ttb+32)*H2 + j]);
      ebp23[ii] = pk_bf16(ebb[(size_t)(ttb+64 )*H2 + j], ebb[(size_t)(ttb+96)*H2 + j]);
      vsum_mine += att_v[j];
    }
  }
  if (tid < H2) wvs[tid] = -2.0f*att_v[tid];
  if (tid < 128) ((float4*)eqs[0])[tid] = ((const float4*)(eqg + ((size_t)b*T + t0)*H2))[tid];
  __syncthreads();
  int buf = 0;
  for (int tq=0; tq<64; tq+=2){
    int cur = (tq>>1)&1;
    if (tq+2 < 64 && tid < 128)
      ((float4*)eqs[buf^1])[tid] = ((const float4*)(eqg + ((size_t)b*T + t0+tq+2)*H2))[tid];
    const float* eq0 = eqs[buf];
    const float* eq1 = eqs[buf] + H2;
    float a00=vsum_mine,a01=vsum_mine,a02=vsum_mine,a03=vsum_mine;
    float a10=vsum_mine,a11=vsum_mine,a12=vsum_mine,a13=vsum_mine;
    #pragma unroll
    for (int ii=0; ii<16; ii++){
      float e0=bflo(ebp01[ii]), e1=bfhi(ebp01[ii]);
      float e2=bflo(ebp23[ii]), e3=bfhi(ebp23[ii]);
      float q0=eq0[jq+16*ii], q1=eq1[jq+16*ii];
      float w=wvs[jq+16*ii];
      a00 = fmaf(w, fast_rcp(fmaf(e0,q0,1.f)), a00);
      a01 = fmaf(w, fast_rcp(fmaf(e1,q0,1.f)), a01);
      a02 = fmaf(w, fast_rcp(fmaf(e2,q0,1.f)), a02);
      a03 = fmaf(w, fast_rcp(fmaf(e3,q0,1.f)), a03);
      a10 = fmaf(w, fast_rcp(fmaf(e0,q1,1.f)), a10);
      a11 = fmaf(w, fast_rcp(fmaf(e1,q1,1.f)), a11);
      a12 = fmaf(w, fast_rcp(fmaf(e2,q1,1.f)), a12);
      a13 = fmaf(w, fast_rcp(fmaf(e3,q1,1.f)), a13);
    }
    #pragma unroll
    for (int off=1; off<16; off<<=1){
      a00 += __shfl_xor(a00,off); a01 += __shfl_xor(a01,off);
      a02 += __shfl_xor(a02,off); a03 += __shfl_xor(a03,off);
      a10 += __shfl_xor(a10,off); a11 += __shfl_xor(a11,off);
      a12 += __shfl_xor(a12,off); a13 += __shfl_xor(a13,off);
    }
    if (jq==0){
      scl[cur][0][ttb]=__expf(a00); scl[cur][0][ttb+32]=__expf(a01);
      scl[cur][0][ttb+64]=__expf(a02); scl[cur][0][ttb+96]=__expf(a03);
      scl[cur][1][ttb]=__expf(a10); scl[cur][1][ttb+32]=__expf(a11);
      scl[cur][1][ttb+64]=__expf(a12); scl[cur][1][ttb+96]=__expf(a13);
    }
    __syncthreads();                          // A: scl[cur] ready
    if (tid < 256){
      int row = tid>>7;
      float e = scl[cur][row][tid&127];
      #pragma unroll
      for (int off=1; off<64; off<<=1) e += __shfl_xor(e,off);
      if ((tid&63)==0) wsum4[cur][tid>>6]=e;
    }
    __syncthreads();                          // B: wsum ready
    if (tid < 128){
      int row = tid>>6, i = tid&63;
      float tot = wsum4[cur][row*2] + wsum4[cur][row*2+1];
      float inv = fast_rcp(tot*128.0f);
      sc16[((size_t)b*T + t0+tq+row)*64 + i] =
        pk_f16(scl[cur][row][2*i]*inv, scl[cur][row][2*i+1]*inv);
    }
    buf ^= 1;
  }
}

// ---------- PV: ctx[b,t,:] = sc16[t] . on_s  (f16 dot2, V column in 64 regs) ----------
__global__ __launch_bounds__(256,4) void pv_k(
  const uint32* __restrict__ sc16, const uint32* __restrict__ onsT, float* __restrict__ ctx)
{
  int b  = blockIdx.x >> 3;
  int t0 = (blockIdx.x & 7) * 16;
  int tid = threadIdx.x;                 // output column j
  __shared__ uint32 scs[16][64];
  uint4 vreg[16];
  {
    const uint4* vp = (const uint4*)(onsT + ((size_t)b*H2 + tid)*64);
    #pragma unroll
    for (int k=0;k<16;k++) vreg[k] = vp[k];
  }
  for (int i=tid;i<1024;i+=256) ((uint32*)scs)[i] = sc16[((size_t)b*T + t0)*64 + i];
  __syncthreads();
  for (int qt=0; qt<16; qt++){
    float a0=0.f,a1=0.f,a2=0.f,a3=0.f;
    #pragma unroll
    for (int k=0;k<16;k++){
      a0 = dot2(scs[qt][4*k+0], vreg[k].x, a0);
      a1 = dot2(scs[qt][4*k+1], vreg[k].y, a1);
      a2 = dot2(scs[qt][4*k+2], vreg[k].z, a2);
      a3 = dot2(scs[qt][4*k+3], vreg[k].w, a3);
    }
    ctx[((size_t)b*T + t0+qt)*H2 + tid] = (a0+a1)+(a2+a3);
  }
}

// ---------- output projection, all (b,t) ----------
__global__ __launch_bounds__(256) void outproj_k(
  const float* __restrict__ h_state, const float* __restrict__ ctx,
  const float* __restrict__ WoutT, const float* __restrict__ bout, float* __restrict__ out)
{
  int m0 = blockIdx.x*16; int b = m0>>7; int t0 = m0&127;
  __shared__ __align__(16) float rb[16][G];
  int tid=threadIdx.x;
  for (int i=tid;i<16*G;i+=256){
    int r=i>>9, c=i&511;
    int t = t0+r;
    float v;
    if (c<H)       v = h_state[(size_t)(t+1)*2*B*H + (size_t)b*H + c];
    else if (c<H2) v = h_state[(size_t)(t+1)*2*B*H + (size_t)B*H + (size_t)b*H + (c-H)];
    else           v = ctx[((size_t)(m0+r))*H2 + (c-H2)];
    rb[r][c]=v;
  }
  __syncthreads();
  for (int o=tid;o<16*D;o+=256){
    int r=o/D, j=o-r*D;
    float acc=bout[j];
    for (int k4=0;k4<128;k4++){
      int k=4*k4;
      float4 rv = *(const float4*)&rb[r][k];
      acc += rv.x*WoutT[(size_t)k*D+j]     + rv.y*WoutT[(size_t)(k+1)*D+j]
           + rv.z*WoutT[(size_t)(k+2)*D+j] + rv.w*WoutT[(size_t)(k+3)*D+j];
    }
    out[((size_t)(m0+r))*D + j]=acc;
  }
}

extern "C" void kernel_launch(void* const* d_in, const int* in_sizes, int n_in,
                              void* d_out, int out_size, void* d_ws, size_t ws_size,
                              hipStream_t stream) {
  const float* x      =(const float*)d_in[0];
  const float* eps_z  =(const float*)d_in[1];
  const float* eps_on =(const float*)d_in[2];
  const float* enc_Wih=(const float*)d_in[3];
  const float* enc_Whh=(const float*)d_in[4];
  const float* enc_b  =(const float*)d_in[5];
  const float* dec_Wih=(const float*)d_in[6];
  const float* dec_Whh=(const float*)d_in[7];
  const float* dec_b  =(const float*)d_in[8];
  const float* Wzmu=(const float*)d_in[9];  const float* bzmu=(const float*)d_in[10];
  const float* Wzlv=(const float*)d_in[11]; const float* bzlv=(const float*)d_in[12];
  const float* Womu=(const float*)d_in[13]; const float* bomu=(const float*)d_in[14];
  const float* Wolv=(const float*)d_in[15]; const float* bolv=(const float*)d_in[16];
  const float* att_v=(const float*)d_in[17];
  const float* att_W1=(const float*)d_in[18]; const float* att_b1=(const float*)d_in[19];
  const float* att_W2=(const float*)d_in[20]; const float* att_b2=(const float*)d_in[21];
  const float* Wout=(const float*)d_in[22];  const float* bout=(const float*)d_in[23];
  float* out=(float*)d_out;
  float* ws=(float*)d_ws;
  (void)ws_size; (void)n_in; (void)in_sizes; (void)out_size;

  size_t o=0;
  float* encWihT=ws+o; o+=2*D*G;
  float* decWihT=ws+o; o+=2*D*G;
  float* WzmuT=ws+o; o+=H*H;
  float* WzlvT=ws+o; o+=H*H;
  float* WomuT=ws+o; o+=H2*H2;
  float* WolvT=ws+o; o+=H2*H2;
  float* W1T  =ws+o; o+=H2*H2;
  float* W2T  =ws+o; o+=H2*H2;
  float* WoutT=ws+o; o+=G*D;
  uint32* wpkE=(uint32*)(ws+o); o+=65536;
  uint32* wpkD=(uint32*)(ws+o); o+=65536;
  float* h_fin=ws+o; o+=2*B*H;
  __half* on16=(__half*)(ws+o); o+=(size_t)B*T*H2/2;
  float* h_state=ws+o; o+=(size_t)(T+1)*2*B*H;
  float* Abase=ws+o; o+=16777216;                // 64MB: xgh -> {eqg 32MB | ctx 32MB}
  float* Cbase=ws+o; o+=14680064;                // 56MB: onsT 16MB + ebg 32MB + sc16 8MB

  __half* xgh = (__half*)Abase;
  float* eqg  = Abase;
  float* ctx  = Abase + 8388608;
  uint32* onsT = (uint32*)Cbase;
  float* ebg  = Cbase + 4194304;
  uint32* sc16 = (uint32*)(Cbase + 4194304 + 8388608);

  PrepArgs pa;
  const float* srcs[9]={enc_Wih,dec_Wih,Wzmu,Wzlv,Womu,Wolv,att_W1,att_W2,Wout};
  float* dsts[9]={encWihT,decWihT,WzmuT,WzlvT,WomuT,WolvT,W1T,W2T,WoutT};
  int Gns[9]={2,2,1,1,1,1,1,1,1};
  int Rs[9]={G,G,H,H,H2,H2,H2,H2,D};
  int Cs[9]={D,D,H,H,H2,H2,H2,H2,G};
  for(int i=0;i<9;i++){pa.src[i]=srcs[i];pa.dst[i]=dsts[i];pa.Gn[i]=Gns[i];pa.R[i]=Rs[i];pa.C[i]=Cs[i];}
  prep_k<<<288,256,0,stream>>>(pa);
  pack_whh_k<<<512,256,0,stream>>>(enc_Whh, dec_Whh, wpkE, wpkD);

  // encoder phase
  xg_k<<<4096,256,0,stream>>>(x, encWihT, enc_b, xgh, 0);
  rec_k<1><<<512,512,0,stream>>>(xgh, wpkE, nullptr, on16, h_fin, nullptr);
  z_k<<<512,128,0,stream>>>(h_fin, WzmuT,bzmu,WzlvT,bzlv,eps_z, h_state);
  onsw2v_k<<<2048,256,0,stream>>>((const uint32*)on16,WomuT,bomu,WolvT,bolv,eps_on,W2T,att_b2,onsT,ebg);

  // decoder phase (xgh reuses region A; eqg overwrites it after rec_k<0>)
  xg_k<<<4096,256,0,stream>>>(x, decWihT, dec_b, xgh, 1);
  rec_k<0><<<512,512,0,stream>>>(xgh, wpkD, h_state, nullptr, nullptr, h_state);

  qp_all_k<<<2048,256,0,stream>>>(h_state, W1T, att_b1, eqg);
  score_k<<<512,512,0,stream>>>(eqg, ebg, att_v, sc16);
  pv_k<<<2048,256,0,stream>>>(sc16, onsT, ctx);
  outproj_k<<<2048,256,0,stream>>>(h_state, ctx, WoutT, bout, out);
}

// Round 10
// 942.654 us; speedup vs baseline: 1.9552x; 1.2243x over previous
//
#include <hip/hip_runtime.h>
#include <hip/hip_fp16.h>

#define B 256
#define T 128
#define D 76
#define H 128
#define G 512   // 4H
#define H2 256  // 2H

typedef unsigned int uint32;
typedef unsigned short ushort16;
typedef _Float16 h2_t __attribute__((ext_vector_type(2)));

__device__ __forceinline__ float sigm(float x){ return 1.0f/(1.0f+__expf(-x)); }
__device__ __forceinline__ float fast_rcp(float x){ float r; asm volatile("v_rcp_f32 %0, %1" : "=v"(r) : "v"(x)); return r; }
__device__ __forceinline__ float fast_tanh(float x){ return 1.0f - 2.0f*fast_rcp(1.0f + __expf(2.0f*x)); }
__device__ __forceinline__ float bflo(uint32 u){ return __uint_as_float(u<<16); }
__device__ __forceinline__ float bfhi(uint32 u){ return __uint_as_float(u & 0xffff0000u); }
__device__ __forceinline__ ushort16 f2bf(float f){ uint32 u=__float_as_uint(f); return (ushort16)((u + 0x7fffu + ((u>>16)&1u))>>16); }
__device__ __forceinline__ float h2f_lo(uint32 u){ return __half2float(__ushort_as_half((unsigned short)(u & 0xffffu))); }
__device__ __forceinline__ float h2f_hi(uint32 u){ return __half2float(__ushort_as_half((unsigned short)(u >> 16))); }
__device__ __forceinline__ uint32 pk_f16(float a, float b){
  return (uint32)__half_as_ushort(__float2half(a)) | ((uint32)__half_as_ushort(__float2half(b))<<16);
}
__device__ __forceinline__ uint32 pk_bf16(float a, float b){
  return (uint32)f2bf(a) | ((uint32)f2bf(b)<<16);
}
__device__ __forceinline__ float dot2(uint32 w, uint32 h, float acc){
  return __builtin_amdgcn_fdot2(__builtin_bit_cast(h2_t, w), __builtin_bit_cast(h2_t, h), acc, false);
}

// ---------- weight transposes (4 segs: enc_Wih, dec_Wih, Wzmu, Wzlv) ----------
struct PrepArgs {
  const float* src[4];
  float* dst[4];
  int Gn[4]; int R[4]; int C[4];
};
__global__ __launch_bounds__(256) void prep_k(PrepArgs a){
  int seg = blockIdx.x >> 5;
  const float* s=a.src[seg]; float* d=a.dst[seg];
  int R=a.R[seg], C=a.C[seg], tot=a.Gn[seg]*R*C;
  for (int i=(blockIdx.x&31)*256+threadIdx.x; i<tot; i+=32*256){
    int g=i/(R*C); int rc=i-g*(R*C); int r=rc/C, c=rc-r*C;
    d[((size_t)g*C+c)*R + r] = s[i];
  }
}

// ---------- pack [N][K] f32 row-major -> [K/2][N] f16-pair u32 (5 segs) ----------
struct Pack2Args { const float* src[5]; uint32* dst[5]; int N[5]; int K[5]; };
__global__ __launch_bounds__(256) void pack2_k(Pack2Args a){
  int seg = blockIdx.x >> 5;
  const float* s=a.src[seg]; uint32* d=a.dst[seg];
  int N=a.N[seg], K=a.K[seg], tot=N*(K>>1);
  for (int i=(blockIdx.x&31)*256+threadIdx.x; i<tot; i+=32*256){
    int k2=i/N, j=i-k2*N;
    float2 w = *(const float2*)(s + (size_t)j*K + 2*k2);
    d[(size_t)k2*N + j] = pk_f16(w.x, w.y);
  }
}

// ---------- pack Whh (enc+dec) f16 k-pairs: wpk[phase][d][k2][j] ----------
__global__ __launch_bounds__(256) void pack_whh_k(
  const float* __restrict__ eWhh, const float* __restrict__ dWhh,
  uint32* __restrict__ wpkE, uint32* __restrict__ wpkD)
{
  int idx = blockIdx.x*256 + threadIdx.x;      // 131072 total
  int phase = idx >> 16;
  int rem = idx & 65535;
  int d = rem >> 15;
  int k2 = (rem >> 9) & 63;
  int j = rem & 511;
  const float* Wsrc = phase ? dWhh : eWhh;
  float2 wa = *(const float2*)(Wsrc + ((size_t)(d*512 + j))*128 + 2*k2);
  (phase ? wpkD : wpkE)[rem] = pk_f16(wa.x, wa.y);
}

// ---------- xg = x @ Wih^T + b, flat f16 [d][b][t][512]. shift=1 for decoder ----------
__global__ __launch_bounds__(256) void xg_k(
  const float* __restrict__ x, const float* __restrict__ WihT, const float* __restrict__ bias,
  __half* __restrict__ xgh, int shift)
{
  int d = blockIdx.x >> 11;
  int blk = blockIdx.x & 2047;
  int b = blk >> 3, t0 = (blk & 7) * 16;
  int tid = threadIdx.x;
  __shared__ __align__(16) float xs[16][D];
  for (int i=tid;i<16*D;i+=256){
    int r=i/D, k=i-r*D, ts=t0+r-shift;
    xs[r][k] = (ts>=0) ? x[((size_t)b*T+ts)*D + k] : 0.f;
  }
  __syncthreads();
  const float* Wi = WihT + (size_t)d*D*G;
  float a0[16], a1[16];
  #pragma unroll
  for(int r=0;r<16;r++){a0[r]=0.f;a1[r]=0.f;}
  for (int k4=0;k4<19;k4++){
    const float* Wk = Wi + (size_t)(4*k4)*G + tid;
    float w00=Wk[0],     w01=Wk[256];
    float w10=Wk[G],     w11=Wk[G+256];
    float w20=Wk[2*G],   w21=Wk[2*G+256];
    float w30=Wk[3*G],   w31=Wk[3*G+256];
    #pragma unroll
    for(int r=0;r<16;r++){
      float4 xv = *(const float4*)&xs[r][4*k4];
      a0[r] += xv.x*w00 + xv.y*w10 + xv.z*w20 + xv.w*w30;
      a1[r] += xv.x*w01 + xv.y*w11 + xv.z*w21 + xv.w*w31;
    }
  }
  float bb0=bias[d*G+tid], bb1=bias[d*G+tid+256];
  #pragma unroll
  for(int r=0;r<16;r++){
    size_t row = (size_t)(d*B + b)*T + (t0+r);
    xgh[row*512 + tid]       = __float2half(a0[r]+bb0);
    xgh[row*512 + tid + 256] = __float2half(a1[r]+bb1);
  }
}

// ---------- recurrence: block=(dir,b) 512 thr; weights in 64 VGPRs; dot2; xg prefetch ----------
// ENC=1: writes on16 + h_fin(f32). ENC=0: h0 is f16 h16[0]; writes h16[t+1] (shfl-paired).
template<int ENC>
__global__ __launch_bounds__(512,2) void rec_k(
  const __half* __restrict__ xgh, const uint32* __restrict__ wpk,
  const __half* __restrict__ h16r, __half* __restrict__ on16,
  float* __restrict__ h_fin, uint32* __restrict__ h16w)
{
  int d = blockIdx.x >> 8;
  int b = blockIdx.x & 255;
  int tid = threadIdx.x;               // gate j in [0,512)
  __shared__ float gl[G];
  __shared__ __half hs_h[H];
  uint32 wreg[64];
  const uint32* wp = wpk + (size_t)d*64*512;
  #pragma unroll
  for (int k2=0;k2<64;k2++) wreg[k2] = wp[k2*512 + tid];
  if (tid < H){
    if (ENC) hs_h[tid] = __float2half(0.f);
    else     hs_h[tid] = h16r[((size_t)d*B + b)*H + tid];   // h16[t=0]
  }
  float creg = 0.f, hlast = 0.f;
  const __half* xrow = xgh + (size_t)(d*B + b)*T*512;
  int te0 = ENC ? (d ? (T-1) : 0) : 0;
  __half xr_next = xrow[(size_t)te0*512 + tid];
  __syncthreads();
  for (int t=0;t<T;t++){
    int te = ENC ? (d ? (T-1-t) : t) : t;
    __half xr = xr_next;
    if (t+1 < T){
      int tn = ENC ? (d ? (T-2-t) : (t+1)) : (t+1);
      xr_next = xrow[(size_t)tn*512 + tid];
    }
    const uint32* h32 = (const uint32*)hs_h;
    float acc0 = 0.f, acc1 = 0.f;
    #pragma unroll
    for (int k2=0;k2<64;k2+=2){
      acc0 = dot2(wreg[k2],   h32[k2],   acc0);
      acc1 = dot2(wreg[k2+1], h32[k2+1], acc1);
    }
    gl[tid] = acc0 + acc1 + __half2float(xr);
    __syncthreads();
    if (tid < H){
      float ii=sigm(gl[tid]), ff=sigm(gl[128+tid]);
      float gg=fast_tanh(gl[256+tid]), oo=fast_tanh(gl[384+tid]);
      // NOTE: oo must be sigmoid, not tanh -- keep correct below
      oo = sigm(gl[384+tid]);
      creg = ff*creg + ii*gg;
      float hv = oo*fast_tanh(creg);
      hlast = hv;
      hs_h[tid] = __float2half(hv);
      if (ENC){
        on16[((size_t)b*T + te)*H2 + d*H + tid] = __float2half(hv);
      } else {
        float nb = __shfl_xor(hv, 1);
        if ((tid&1)==0)
          h16w[(((size_t)(t+1)*2 + d)*B + b)*64 + (tid>>1)] = pk_f16(hv, nb);
      }
    }
    __syncthreads();
  }
  if (ENC && tid < H) h_fin[(size_t)d*B*H + (size_t)b*H + tid] = hlast;
}

// ---------- z = mu + eps*exp(0.5 lv) -> h16[0] (f16 pairs) ----------
__global__ __launch_bounds__(128) void z_k(
  const float* __restrict__ h_fin, const float* __restrict__ WzmuT, const float* __restrict__ bzmu,
  const float* __restrict__ WzlvT, const float* __restrict__ bzlv, const float* __restrict__ eps_z,
  uint32* __restrict__ h16w)
{
  __shared__ float hr[H];
  int d = blockIdx.x >> 8; int b = blockIdx.x & 255;
  int j = threadIdx.x;
  hr[j] = h_fin[(size_t)d*B*H + (size_t)b*H + j];
  __syncthreads();
  float mu=bzmu[j], lv=bzlv[j];
  #pragma unroll 4
  for(int k=0;k<H;k++){ float hv=hr[k]; mu+=hv*WzmuT[k*H+j]; lv+=hv*WzlvT[k*H+j]; }
  float z = mu + eps_z[(size_t)d*B*H + (size_t)b*H + j]*__expf(0.5f*lv);
  float nb = __shfl_xor(z, 1);
  if ((j&1)==0)
    h16w[(((size_t)0*2 + d)*B + b)*64 + (j>>1)] = pk_f16(z, nb);
}

// ---------- fused on_s (f16 dot2 GEMMs): onsT + eb ----------
__global__ __launch_bounds__(256) void onsw2v_k(
  const uint32* __restrict__ on32, const uint32* __restrict__ wpmu, const float* __restrict__ bomu,
  const uint32* __restrict__ wplv, const float* __restrict__ bolv, const float* __restrict__ eps_on,
  const uint32* __restrict__ wp2, const float* __restrict__ b2,
  uint32* __restrict__ onsT, float* __restrict__ ebg)
{
  __shared__ uint32 tl[16][128];     // on (f16 pairs along k)
  __shared__ uint32 t2p[16][128];    // on_s (f16 pairs along j)
  size_t row0=(size_t)blockIdx.x*16;
  int b = (int)(row0 >> 7), t0 = (int)(row0 & 127);
  int tid=threadIdx.x;
  for(int i=tid;i<16*128;i+=256) ((uint32*)tl)[i] = on32[row0*128 + i];
  __syncthreads();
  float am[16], al[16];
  #pragma unroll
  for(int r=0;r<16;r++){am[r]=0.f;al[r]=0.f;}
  for(int k4=0;k4<64;k4++){
    int k2=2*k4;
    uint32 wm0=wpmu[(size_t)k2*H2+tid], wm1=wpmu[(size_t)(k2+1)*H2+tid];
    uint32 wl0=wplv[(size_t)k2*H2+tid], wl1=wplv[(size_t)(k2+1)*H2+tid];
    #pragma unroll
    for(int r=0;r<16;r++){
      uint2 u = *(const uint2*)&tl[r][k2];
      am[r]=dot2(u.x,wm0,am[r]); am[r]=dot2(u.y,wm1,am[r]);
      al[r]=dot2(u.x,wl0,al[r]); al[r]=dot2(u.y,wl1,al[r]);
    }
  }
  float bm=bomu[tid], bl=bolv[tid];
  float vv[16];
  #pragma unroll
  for(int r=0;r<16;r++){
    size_t row=row0+r;
    vv[r] = am[r]+bm + eps_on[row*H2+tid]*__expf(0.5f*(al[r]+bl));
  }
  // pack on_s pairs along j via shfl (even lanes write)
  #pragma unroll
  for(int r=0;r<16;r++){
    float nb = __shfl_xor(vv[r], 1);
    if ((tid&1)==0) t2p[r][tid>>1] = pk_f16(vv[r], nb);
  }
  __syncthreads();
  // on_s^T f16 t-pairs for PV: onsT[(b*256 + j)*64 + t/2]
  #pragma unroll
  for(int rr=0;rr<8;rr++){
    uint32 ua = t2p[2*rr][tid>>1], ub = t2p[2*rr+1][tid>>1];
    uint32 ha = (tid&1) ? (ua>>16) : (ua & 0xffffu);
    uint32 hb = (tid&1) ? (ub>>16) : (ub & 0xffffu);
    onsT[((size_t)b*H2 + tid)*64 + (t0>>1) + rr] = ha | (hb<<16);
  }
  // eb = exp(2*(on_s @ W2^T + b2))
  float ac[16];
  #pragma unroll
  for(int r=0;r<16;r++) ac[r]=0.f;
  for(int k4=0;k4<64;k4++){
    int k2=2*k4;
    uint32 w0=wp2[(size_t)k2*H2+tid], w1=wp2[(size_t)(k2+1)*H2+tid];
    #pragma unroll
    for(int r=0;r<16;r++){
      uint2 u = *(const uint2*)&t2p[r][k2];
      ac[r]=dot2(u.x,w0,ac[r]); ac[r]=dot2(u.y,w1,ac[r]);
    }
  }
  float bb=b2[tid];
  #pragma unroll
  for(int r=0;r<16;r++) ebg[(row0+r)*H2+tid]=__expf(2.0f*(ac[r]+bb));
}

// ---------- eq = exp(2*(concat(h0,h1)@W1T+b1)) via f16 dot2 ----------
__global__ __launch_bounds__(256) void qp_all_k(
  const uint32* __restrict__ h16, const uint32* __restrict__ wp1, const float* __restrict__ b1,
  float* __restrict__ eqg)
{
  int m0 = blockIdx.x*16; int b = m0>>7; int t0 = m0&127;
  __shared__ uint32 tile[16][128];
  int tid=threadIdx.x;
  for (int i=tid;i<16*128;i+=256){
    int r=i>>7, c=i&127; int dd=c>>6, kk2=c&63;
    tile[r][c] = h16[(((size_t)(t0+r)*2 + dd)*B + b)*64 + kk2];
  }
  __syncthreads();
  float ac[16];
  #pragma unroll
  for(int r=0;r<16;r++) ac[r]=0.f;
  for(int k4=0;k4<64;k4++){
    int k2=2*k4;
    uint32 w0=wp1[(size_t)k2*H2+tid], w1=wp1[(size_t)(k2+1)*H2+tid];
    #pragma unroll
    for(int r=0;r<16;r++){
      uint2 u = *(const uint2*)&tile[r][k2];
      ac[r]=dot2(u.x,w0,ac[r]); ac[r]=dot2(u.y,w1,ac[r]);
    }
  }
  float bb=b1[tid];
  #pragma unroll
  for(int r=0;r<16;r++) eqg[(size_t)(m0+r)*H2+tid]=__expf(2.0f*(ac[r]+bb));
}

// ---------- scores: block=(b,t-half), TQ=2, eb in 32 regs; writes normalized f16 weights ----------
__global__ __launch_bounds__(512,2) void score_k(
  const float* __restrict__ eqg, const float* __restrict__ ebg,
  const float* __restrict__ att_v, uint32* __restrict__ sc16)
{
  int b  = blockIdx.x >> 1;
  int t0 = (blockIdx.x & 1) * 64;
  int tid = threadIdx.x;
  int jq = tid & 15, ttb = tid >> 4;
  __shared__ __align__(16) float eqs[2][2*H2];
  __shared__ __align__(16) float scl[2][2][T];
  __shared__ float wsum4[2][4];
  __shared__ float wvs[H2];
  uint32 ebp01[16], ebp23[16];
  float vsum_mine = 0.f;
  {
    const float* ebb = ebg + (size_t)b*T*H2;
    #pragma unroll
    for (int ii=0;ii<16;ii++){
      int j = jq + 16*ii;
      ebp01[ii] = pk_bf16(ebb[(size_t)(ttb    )*H2 + j], ebb[(size_t)(ttb+32)*H2 + j]);
      ebp23[ii] = pk_bf16(ebb[(size_t)(ttb+64 )*H2 + j], ebb[(size_t)(ttb+96)*H2 + j]);
      vsum_mine += att_v[j];
    }
  }
  if (tid < H2) wvs[tid] = -2.0f*att_v[tid];
  if (tid < 128) ((float4*)eqs[0])[tid] = ((const float4*)(eqg + ((size_t)b*T + t0)*H2))[tid];
  __syncthreads();
  int buf = 0;
  for (int tq=0; tq<64; tq+=2){
    int cur = (tq>>1)&1;
    if (tq+2 < 64 && tid < 128)
      ((float4*)eqs[buf^1])[tid] = ((const float4*)(eqg + ((size_t)b*T + t0+tq+2)*H2))[tid];
    const float* eq0 = eqs[buf];
    const float* eq1 = eqs[buf] + H2;
    float a00=vsum_mine,a01=vsum_mine,a02=vsum_mine,a03=vsum_mine;
    float a10=vsum_mine,a11=vsum_mine,a12=vsum_mine,a13=vsum_mine;
    #pragma unroll
    for (int ii=0; ii<16; ii++){
      float e0=bflo(ebp01[ii]), e1=bfhi(ebp01[ii]);
      float e2=bflo(ebp23[ii]), e3=bfhi(ebp23[ii]);
      float q0=eq0[jq+16*ii], q1=eq1[jq+16*ii];
      float w=wvs[jq+16*ii];
      a00 = fmaf(w, fast_rcp(fmaf(e0,q0,1.f)), a00);
      a01 = fmaf(w, fast_rcp(fmaf(e1,q0,1.f)), a01);
      a02 = fmaf(w, fast_rcp(fmaf(e2,q0,1.f)), a02);
      a03 = fmaf(w, fast_rcp(fmaf(e3,q0,1.f)), a03);
      a10 = fmaf(w, fast_rcp(fmaf(e0,q1,1.f)), a10);
      a11 = fmaf(w, fast_rcp(fmaf(e1,q1,1.f)), a11);
      a12 = fmaf(w, fast_rcp(fmaf(e2,q1,1.f)), a12);
      a13 = fmaf(w, fast_rcp(fmaf(e3,q1,1.f)), a13);
    }
    #pragma unroll
    for (int off=1; off<16; off<<=1){
      a00 += __shfl_xor(a00,off); a01 += __shfl_xor(a01,off);
      a02 += __shfl_xor(a02,off); a03 += __shfl_xor(a03,off);
      a10 += __shfl_xor(a10,off); a11 += __shfl_xor(a11,off);
      a12 += __shfl_xor(a12,off); a13 += __shfl_xor(a13,off);
    }
    if (jq==0){
      scl[cur][0][ttb]=__expf(a00); scl[cur][0][ttb+32]=__expf(a01);
      scl[cur][0][ttb+64]=__expf(a02); scl[cur][0][ttb+96]=__expf(a03);
      scl[cur][1][ttb]=__expf(a10); scl[cur][1][ttb+32]=__expf(a11);
      scl[cur][1][ttb+64]=__expf(a12); scl[cur][1][ttb+96]=__expf(a13);
    }
    __syncthreads();                          // A: scl[cur] ready
    if (tid < 256){
      int row = tid>>7;
      float e = scl[cur][row][tid&127];
      #pragma unroll
      for (int off=1; off<64; off<<=1) e += __shfl_xor(e,off);
      if ((tid&63)==0) wsum4[cur][tid>>6]=e;
    }
    __syncthreads();                          // B: wsum ready
    if (tid < 128){
      int row = tid>>6, i = tid&63;
      float tot = wsum4[cur][row*2] + wsum4[cur][row*2+1];
      float inv = fast_rcp(tot*128.0f);
      sc16[((size_t)b*T + t0+tq+row)*64 + i] =
        pk_f16(scl[cur][row][2*i]*inv, scl[cur][row][2*i+1]*inv);
    }
    buf ^= 1;
  }
}

// ---------- PV: ctx16 = sc16 . on_s (f16 dot2, V column in 64 regs; f16-pair output) ----------
__global__ __launch_bounds__(256,4) void pv_k(
  const uint32* __restrict__ sc16, const uint32* __restrict__ onsT, uint32* __restrict__ ctx16)
{
  int b  = blockIdx.x >> 3;
  int t0 = (blockIdx.x & 7) * 16;
  int tid = threadIdx.x;                 // output column j
  __shared__ uint32 scs[16][64];
  uint4 vreg[16];
  {
    const uint4* vp = (const uint4*)(onsT + ((size_t)b*H2 + tid)*64);
    #pragma unroll
    for (int k=0;k<16;k++) vreg[k] = vp[k];
  }
  for (int i=tid;i<1024;i+=256) ((uint32*)scs)[i] = sc16[((size_t)b*T + t0)*64 + i];
  __syncthreads();
  for (int qt=0; qt<16; qt++){
    float a0=0.f,a1=0.f,a2=0.f,a3=0.f;
    #pragma unroll
    for (int k=0;k<16;k++){
      a0 = dot2(scs[qt][4*k+0], vreg[k].x, a0);
      a1 = dot2(scs[qt][4*k+1], vreg[k].y, a1);
      a2 = dot2(scs[qt][4*k+2], vreg[k].z, a2);
      a3 = dot2(scs[qt][4*k+3], vreg[k].w, a3);
    }
    float mine = (a0+a1)+(a2+a3);
    float nb = __shfl_xor(mine, 1);
    if ((tid&1)==0)
      ctx16[((size_t)b*T + t0+qt)*128 + (tid>>1)] = pk_f16(mine, nb);
  }
}

// ---------- output projection via f16 dot2 ----------
__global__ __launch_bounds__(256) void outproj_k(
  const uint32* __restrict__ h16, const uint32* __restrict__ ctx16,
  const uint32* __restrict__ wpout, const float* __restrict__ bout, float* __restrict__ out)
{
  int m0 = blockIdx.x*16; int b = m0>>7; int t0 = m0&127;
  __shared__ uint32 rb[16][256];
  int tid=threadIdx.x;
  for (int i=tid;i<16*256;i+=256){
    int r=i>>8, c=i&255;
    int t = t0+r;
    uint32 v;
    if (c<64)        v = h16[(((size_t)(t+1)*2 + 0)*B + b)*64 + c];
    else if (c<128)  v = h16[(((size_t)(t+1)*2 + 1)*B + b)*64 + (c-64)];
    else             v = ctx16[((size_t)(m0+r))*128 + (c-128)];
    rb[r][c]=v;
  }
  __syncthreads();
  for (int o=tid;o<16*D;o+=256){
    int r=o/D, j=o-r*D;
    float acc=bout[j];
    for (int k4=0;k4<64;k4++){
      uint4 u = *(const uint4*)&rb[r][4*k4];
      acc = dot2(u.x, wpout[(size_t)(4*k4+0)*D+j], acc);
      acc = dot2(u.y, wpout[(size_t)(4*k4+1)*D+j], acc);
      acc = dot2(u.z, wpout[(size_t)(4*k4+2)*D+j], acc);
      acc = dot2(u.w, wpout[(size_t)(4*k4+3)*D+j], acc);
    }
    out[((size_t)(m0+r))*D + j]=acc;
  }
}

extern "C" void kernel_launch(void* const* d_in, const int* in_sizes, int n_in,
                              void* d_out, int out_size, void* d_ws, size_t ws_size,
                              hipStream_t stream) {
  const float* x      =(const float*)d_in[0];
  const float* eps_z  =(const float*)d_in[1];
  const float* eps_on =(const float*)d_in[2];
  const float* enc_Wih=(const float*)d_in[3];
  const float* enc_Whh=(const float*)d_in[4];
  const float* enc_b  =(const float*)d_in[5];
  const float* dec_Wih=(const float*)d_in[6];
  const float* dec_Whh=(const float*)d_in[7];
  const float* dec_b  =(const float*)d_in[8];
  const float* Wzmu=(const float*)d_in[9];  const float* bzmu=(const float*)d_in[10];
  const float* Wzlv=(const float*)d_in[11]; const float* bzlv=(const float*)d_in[12];
  const float* Womu=(const float*)d_in[13]; const float* bomu=(const float*)d_in[14];
  const float* Wolv=(const float*)d_in[15]; const float* bolv=(const float*)d_in[16];
  const float* att_v=(const float*)d_in[17];
  const float* att_W1=(const float*)d_in[18]; const float* att_b1=(const float*)d_in[19];
  const float* att_W2=(const float*)d_in[20]; const float* att_b2=(const float*)d_in[21];
  const float* Wout=(const float*)d_in[22];  const float* bout=(const float*)d_in[23];
  float* out=(float*)d_out;
  float* ws=(float*)d_ws;
  (void)ws_size; (void)n_in; (void)in_sizes; (void)out_size;

  size_t o=0;
  float* encWihT=ws+o; o+=2*D*G;
  float* decWihT=ws+o; o+=2*D*G;
  float* WzmuT=ws+o; o+=H*H;
  float* WzlvT=ws+o; o+=H*H;
  uint32* wpkE=(uint32*)(ws+o); o+=65536;
  uint32* wpkD=(uint32*)(ws+o); o+=65536;
  uint32* wpmu=(uint32*)(ws+o); o+=32768;   // [k2=128][256]
  uint32* wplv=(uint32*)(ws+o); o+=32768;
  uint32* wp1 =(uint32*)(ws+o); o+=32768;
  uint32* wp2 =(uint32*)(ws+o); o+=32768;
  uint32* wpout=(uint32*)(ws+o); o+=19456;  // [k2=256][76]
  float* h_fin=ws+o; o+=2*B*H;
  __half* on16=(__half*)(ws+o); o+=(size_t)B*T*H2/2;
  uint32* h16 =(uint32*)(ws+o); o+=(size_t)(T+1)*2*B*64;   // f16 pairs [t][d][b][h/2]
  float* Abase=ws+o; o+=16777216;                // 64MB: xgh -> {eqg 32MB | ctx16 16MB}
  float* Cbase=ws+o; o+=14680064;                // 56MB: onsT 16MB + ebg 32MB + sc16 8MB

  __half* xgh = (__half*)Abase;
  float* eqg  = Abase;
  uint32* ctx16 = (uint32*)(Abase + 8388608);
  uint32* onsT = (uint32*)Cbase;
  float* ebg  = Cbase + 4194304;
  uint32* sc16 = (uint32*)(Cbase + 4194304 + 8388608);

  PrepArgs pa;
  {
    const float* srcs[4]={enc_Wih,dec_Wih,Wzmu,Wzlv};
    float* dsts[4]={encWihT,decWihT,WzmuT,WzlvT};
    int Gns[4]={2,2,1,1};
    int Rs[4]={G,G,H,H};
    int Cs[4]={D,D,H,H};
    for(int i=0;i<4;i++){pa.src[i]=srcs[i];pa.dst[i]=dsts[i];pa.Gn[i]=Gns[i];pa.R[i]=Rs[i];pa.C[i]=Cs[i];}
  }
  Pack2Args p2;
  {
    const float* srcs[5]={Womu,Wolv,att_W1,att_W2,Wout};
    uint32* dsts[5]={wpmu,wplv,wp1,wp2,wpout};
    int Ns[5]={H2,H2,H2,H2,D};
    int Ks[5]={H2,H2,H2,H2,G};
    for(int i=0;i<5;i++){p2.src[i]=srcs[i];p2.dst[i]=dsts[i];p2.N[i]=Ns[i];p2.K[i]=Ks[i];}
  }
  prep_k<<<128,256,0,stream>>>(pa);
  pack2_k<<<160,256,0,stream>>>(p2);
  pack_whh_k<<<512,256,0,stream>>>(enc_Whh, dec_Whh, wpkE, wpkD);

  // encoder phase
  xg_k<<<4096,256,0,stream>>>(x, encWihT, enc_b, xgh, 0);
  rec_k<1><<<512,512,0,stream>>>(xgh, wpkE, nullptr, on16, h_fin, nullptr);
  z_k<<<512,128,0,stream>>>(h_fin, WzmuT,bzmu,WzlvT,bzlv,eps_z, h16);
  onsw2v_k<<<2048,256,0,stream>>>((const uint32*)on16,wpmu,bomu,wplv,bolv,eps_on,wp2,att_b2,onsT,ebg);

  // decoder phase (xgh reuses region A; eqg overwrites it after rec_k<0>)
  xg_k<<<4096,256,0,stream>>>(x, decWihT, dec_b, xgh, 1);
  rec_k<0><<<512,512,0,stream>>>(xgh, wpkD, (const __half*)h16, nullptr, nullptr, h16);

  qp_all_k<<<2048,256,0,stream>>>(h16, wp1, att_b1, eqg);
  score_k<<<512,512,0,stream>>>(eqg, ebg, att_v, sc16);
  pv_k<<<2048,256,0,stream>>>(sc16, onsT, ctx16);
  outproj_k<<<2048,256,0,stream>>>(h16, ctx16, wpout, bout, out);
}

// Round 11
// 805.847 us; speedup vs baseline: 2.2871x; 1.1698x over previous
//
#include <hip/hip_runtime.h>
#include <hip/hip_fp16.h>

#define B 256
#define T 128
#define D 76
#define H 128
#define G 512   // 4H
#define H2 256  // 2H

typedef unsigned int uint32;
typedef unsigned short ushort16;
typedef _Float16 h2_t __attribute__((ext_vector_type(2)));

__device__ __forceinline__ float sigm(float x){ return 1.0f/(1.0f+__expf(-x)); }
__device__ __forceinline__ float fast_rcp(float x){ float r; asm volatile("v_rcp_f32 %0, %1" : "=v"(r) : "v"(x)); return r; }
__device__ __forceinline__ float fast_tanh(float x){ return 1.0f - 2.0f*fast_rcp(1.0f + __expf(2.0f*x)); }
__device__ __forceinline__ float bflo(uint32 u){ return __uint_as_float(u<<16); }
__device__ __forceinline__ float bfhi(uint32 u){ return __uint_as_float(u & 0xffff0000u); }
__device__ __forceinline__ ushort16 f2bf(float f){ uint32 u=__float_as_uint(f); return (ushort16)((u + 0x7fffu + ((u>>16)&1u))>>16); }
__device__ __forceinline__ uint32 pk_f16(float a, float b){
  return (uint32)__half_as_ushort(__float2half(a)) | ((uint32)__half_as_ushort(__float2half(b))<<16);
}
__device__ __forceinline__ uint32 pk_bf16(float a, float b){
  return (uint32)f2bf(a) | ((uint32)f2bf(b)<<16);
}
__device__ __forceinline__ float dot2(uint32 w, uint32 h, float acc){
  return __builtin_amdgcn_fdot2(__builtin_bit_cast(h2_t, w), __builtin_bit_cast(h2_t, h), acc, false);
}

// ---------- weight transposes (2 segs: Wzmu, Wzlv) ----------
struct PrepArgs {
  const float* src[2];
  float* dst[2];
  int R[2]; int C[2];
};
__global__ __launch_bounds__(256) void prep_k(PrepArgs a){
  int seg = blockIdx.x >> 5;
  const float* s=a.src[seg]; float* d=a.dst[seg];
  int R=a.R[seg], C=a.C[seg], tot=R*C;
  for (int i=(blockIdx.x&31)*256+threadIdx.x; i<tot; i+=32*256){
    int r=i/C, c=i-r*C;
    d[(size_t)c*R + r] = s[i];
  }
}

// ---------- pack [N][K] f32 row-major -> [K/2][N] f16-pair u32 (9 segs) ----------
struct Pack2Args { const float* src[9]; uint32* dst[9]; int N[9]; int K[9]; };
__global__ __launch_bounds__(256) void pack2_k(Pack2Args a){
  int seg = blockIdx.x >> 5;
  const float* s=a.src[seg]; uint32* d=a.dst[seg];
  int N=a.N[seg], K=a.K[seg], tot=N*(K>>1);
  for (int i=(blockIdx.x&31)*256+threadIdx.x; i<tot; i+=32*256){
    int k2=i/N, j=i-k2*N;
    float2 w = *(const float2*)(s + (size_t)j*K + 2*k2);
    d[(size_t)k2*N + j] = pk_f16(w.x, w.y);
  }
}

// ---------- pack Whh (enc+dec) f16 k-pairs: wpk[phase][d][k2][j] ----------
__global__ __launch_bounds__(256) void pack_whh_k(
  const float* __restrict__ eWhh, const float* __restrict__ dWhh,
  uint32* __restrict__ wpkE, uint32* __restrict__ wpkD)
{
  int idx = blockIdx.x*256 + threadIdx.x;      // 131072 total
  int phase = idx >> 16;
  int rem = idx & 65535;
  int d = rem >> 15;
  int k2 = (rem >> 9) & 63;
  int j = rem & 511;
  const float* Wsrc = phase ? dWhh : eWhh;
  float2 wa = *(const float2*)(Wsrc + ((size_t)(d*512 + j))*128 + 2*k2);
  (phase ? wpkD : wpkE)[rem] = pk_f16(wa.x, wa.y);
}

// ---------- xg = x @ Wih^T + b via f16 dot2, flat f16 [d][b][t][512]. shift=1 for decoder ----------
__global__ __launch_bounds__(256) void xg_k(
  const float* __restrict__ x, const uint32* __restrict__ wx, const float* __restrict__ bias,
  __half* __restrict__ xgh, int shift)
{
  int d = blockIdx.x >> 11;
  int blk = blockIdx.x & 2047;
  int b = blk >> 3, t0 = (blk & 7) * 16;
  int tid = threadIdx.x;
  __shared__ __align__(16) uint32 xs[16][40];   // 38 used, rows padded to 160B
  for (int i=tid;i<16*38;i+=256){
    int r=i/38, k2=i-r*38, ts=t0+r-shift;
    float2 xv = (ts>=0) ? *(const float2*)(x + ((size_t)b*T+ts)*D + 2*k2) : make_float2(0.f,0.f);
    xs[r][k2] = pk_f16(xv.x, xv.y);
  }
  __syncthreads();
  const uint32* W = wx + (size_t)d*38*512;
  float a0[16], a1[16];
  #pragma unroll
  for(int r=0;r<16;r++){a0[r]=0.f;a1[r]=0.f;}
  #pragma unroll
  for (int k8=0;k8<9;k8++){
    int k2=4*k8;
    uint32 w00=W[(size_t)(k2+0)*512+tid], w01=W[(size_t)(k2+0)*512+tid+256];
    uint32 w10=W[(size_t)(k2+1)*512+tid], w11=W[(size_t)(k2+1)*512+tid+256];
    uint32 w20=W[(size_t)(k2+2)*512+tid], w21=W[(size_t)(k2+2)*512+tid+256];
    uint32 w30=W[(size_t)(k2+3)*512+tid], w31=W[(size_t)(k2+3)*512+tid+256];
    #pragma unroll
    for(int r=0;r<16;r++){
      uint4 u = *(const uint4*)&xs[r][k2];
      a0[r]=dot2(u.x,w00,a0[r]); a0[r]=dot2(u.y,w10,a0[r]);
      a0[r]=dot2(u.z,w20,a0[r]); a0[r]=dot2(u.w,w30,a0[r]);
      a1[r]=dot2(u.x,w01,a1[r]); a1[r]=dot2(u.y,w11,a1[r]);
      a1[r]=dot2(u.z,w21,a1[r]); a1[r]=dot2(u.w,w31,a1[r]);
    }
  }
  { // tail: k2 = 36, 37
    uint32 w00=W[(size_t)36*512+tid], w01=W[(size_t)36*512+tid+256];
    uint32 w10=W[(size_t)37*512+tid], w11=W[(size_t)37*512+tid+256];
    #pragma unroll
    for(int r=0;r<16;r++){
      uint2 u = *(const uint2*)&xs[r][36];
      a0[r]=dot2(u.x,w00,a0[r]); a0[r]=dot2(u.y,w10,a0[r]);
      a1[r]=dot2(u.x,w01,a1[r]); a1[r]=dot2(u.y,w11,a1[r]);
    }
  }
  float bb0=bias[d*G+tid], bb1=bias[d*G+tid+256];
  #pragma unroll
  for(int r=0;r<16;r++){
    size_t row = (size_t)(d*B + b)*T + (t0+r);
    xgh[row*512 + tid]       = __float2half(a0[r]+bb0);
    xgh[row*512 + tid + 256] = __float2half(a1[r]+bb1);
  }
}

// ---------- recurrence: block=(dir,b) 512 thr; weights in 64 VGPRs; b128 h reads; xg prefetch ----------
// ENC=1: writes on16 + h_fin(f32). ENC=0: h0 is f16 h16[0]; writes h16[t+1] (shfl-paired).
template<int ENC>
__global__ __launch_bounds__(512,2) void rec_k(
  const __half* __restrict__ xgh, const uint32* __restrict__ wpk,
  const __half* __restrict__ h16r, __half* __restrict__ on16,
  float* __restrict__ h_fin, uint32* __restrict__ h16w)
{
  int d = blockIdx.x >> 8;
  int b = blockIdx.x & 255;
  int tid = threadIdx.x;               // gate j in [0,512)
  __shared__ float gl[G];
  __shared__ __align__(16) __half hs_h[H];
  uint32 wreg[64];
  const uint32* wp = wpk + (size_t)d*64*512;
  #pragma unroll
  for (int k2=0;k2<64;k2++) wreg[k2] = wp[k2*512 + tid];
  if (tid < H){
    if (ENC) hs_h[tid] = __float2half(0.f);
    else     hs_h[tid] = h16r[((size_t)d*B + b)*H + tid];   // h16[t=0]
  }
  float creg = 0.f, hlast = 0.f;
  const __half* xrow = xgh + (size_t)(d*B + b)*T*512;
  int te0 = ENC ? (d ? (T-1) : 0) : 0;
  __half xr_next = xrow[(size_t)te0*512 + tid];
  __syncthreads();
  for (int t=0;t<T;t++){
    int te = ENC ? (d ? (T-1-t) : t) : t;
    __half xr = xr_next;
    if (t+1 < T){
      int tn = ENC ? (d ? (T-2-t) : (t+1)) : (t+1);
      xr_next = xrow[(size_t)tn*512 + tid];
    }
    const uint4* h128 = (const uint4*)hs_h;
    float acc0 = 0.f, acc1 = 0.f;
    #pragma unroll
    for (int k8=0;k8<16;k8++){
      uint4 hv4 = h128[k8];
      acc0 = dot2(wreg[4*k8+0], hv4.x, acc0);
      acc1 = dot2(wreg[4*k8+1], hv4.y, acc1);
      acc0 = dot2(wreg[4*k8+2], hv4.z, acc0);
      acc1 = dot2(wreg[4*k8+3], hv4.w, acc1);
    }
    gl[tid] = acc0 + acc1 + __half2float(xr);
    __syncthreads();
    if (tid < H){
      float ii=sigm(gl[tid]), ff=sigm(gl[128+tid]);
      float gg=fast_tanh(gl[256+tid]), oo=sigm(gl[384+tid]);
      creg = ff*creg + ii*gg;
      float hv = oo*fast_tanh(creg);
      hlast = hv;
      hs_h[tid] = __float2half(hv);
      if (ENC){
        on16[((size_t)b*T + te)*H2 + d*H + tid] = __float2half(hv);
      } else {
        float nb = __shfl_xor(hv, 1);
        if ((tid&1)==0)
          h16w[(((size_t)(t+1)*2 + d)*B + b)*64 + (tid>>1)] = pk_f16(hv, nb);
      }
    }
    __syncthreads();
  }
  if (ENC && tid < H) h_fin[(size_t)d*B*H + (size_t)b*H + tid] = hlast;
}

// ---------- z = mu + eps*exp(0.5 lv) -> h16[0] (f16 pairs) ----------
__global__ __launch_bounds__(128) void z_k(
  const float* __restrict__ h_fin, const float* __restrict__ WzmuT, const float* __restrict__ bzmu,
  const float* __restrict__ WzlvT, const float* __restrict__ bzlv, const float* __restrict__ eps_z,
  uint32* __restrict__ h16w)
{
  __shared__ float hr[H];
  int d = blockIdx.x >> 8; int b = blockIdx.x & 255;
  int j = threadIdx.x;
  hr[j] = h_fin[(size_t)d*B*H + (size_t)b*H + j];
  __syncthreads();
  float mu=bzmu[j], lv=bzlv[j];
  #pragma unroll 4
  for(int k=0;k<H;k++){ float hv=hr[k]; mu+=hv*WzmuT[k*H+j]; lv+=hv*WzlvT[k*H+j]; }
  float z = mu + eps_z[(size_t)d*B*H + (size_t)b*H + j]*__expf(0.5f*lv);
  float nb = __shfl_xor(z, 1);
  if ((j&1)==0)
    h16w[(((size_t)0*2 + d)*B + b)*64 + (j>>1)] = pk_f16(z, nb);
}

// ---------- fused on_s (f16 dot2 GEMMs, b128 LDS): onsT + eb ----------
__global__ __launch_bounds__(256) void onsw2v_k(
  const uint32* __restrict__ on32, const uint32* __restrict__ wpmu, const float* __restrict__ bomu,
  const uint32* __restrict__ wplv, const float* __restrict__ bolv, const float* __restrict__ eps_on,
  const uint32* __restrict__ wp2, const float* __restrict__ b2,
  uint32* __restrict__ onsT, float* __restrict__ ebg)
{
  __shared__ __align__(16) uint32 tl[16][128];     // on (f16 pairs along k)
  __shared__ __align__(16) uint32 t2p[16][128];    // on_s (f16 pairs along j)
  size_t row0=(size_t)blockIdx.x*16;
  int b = (int)(row0 >> 7), t0 = (int)(row0 & 127);
  int tid=threadIdx.x;
  for(int i=tid;i<16*128;i+=256) ((uint32*)tl)[i] = on32[row0*128 + i];
  __syncthreads();
  float am[16], al[16];
  #pragma unroll
  for(int r=0;r<16;r++){am[r]=0.f;al[r]=0.f;}
  for(int k8=0;k8<32;k8++){
    int k2=4*k8;
    uint32 wm0=wpmu[(size_t)(k2+0)*H2+tid], wm1=wpmu[(size_t)(k2+1)*H2+tid];
    uint32 wm2=wpmu[(size_t)(k2+2)*H2+tid], wm3=wpmu[(size_t)(k2+3)*H2+tid];
    uint32 wl0=wplv[(size_t)(k2+0)*H2+tid], wl1=wplv[(size_t)(k2+1)*H2+tid];
    uint32 wl2=wplv[(size_t)(k2+2)*H2+tid], wl3=wplv[(size_t)(k2+3)*H2+tid];
    #pragma unroll
    for(int r=0;r<16;r++){
      uint4 u = *(const uint4*)&tl[r][k2];
      am[r]=dot2(u.x,wm0,am[r]); am[r]=dot2(u.y,wm1,am[r]);
      am[r]=dot2(u.z,wm2,am[r]); am[r]=dot2(u.w,wm3,am[r]);
      al[r]=dot2(u.x,wl0,al[r]); al[r]=dot2(u.y,wl1,al[r]);
      al[r]=dot2(u.z,wl2,al[r]); al[r]=dot2(u.w,wl3,al[r]);
    }
  }
  float bm=bomu[tid], bl=bolv[tid];
  float vv[16];
  #pragma unroll
  for(int r=0;r<16;r++){
    size_t row=row0+r;
    vv[r] = am[r]+bm + eps_on[row*H2+tid]*__expf(0.5f*(al[r]+bl));
  }
  // pack on_s pairs along j via shfl (even lanes write)
  #pragma unroll
  for(int r=0;r<16;r++){
    float nb = __shfl_xor(vv[r], 1);
    if ((tid&1)==0) t2p[r][tid>>1] = pk_f16(vv[r], nb);
  }
  __syncthreads();
  // on_s^T f16 t-pairs for PV: onsT[(b*256 + j)*64 + t/2]
  #pragma unroll
  for(int rr=0;rr<8;rr++){
    uint32 ua = t2p[2*rr][tid>>1], ub = t2p[2*rr+1][tid>>1];
    uint32 ha = (tid&1) ? (ua>>16) : (ua & 0xffffu);
    uint32 hb = (tid&1) ? (ub>>16) : (ub & 0xffffu);
    onsT[((size_t)b*H2 + tid)*64 + (t0>>1) + rr] = ha | (hb<<16);
  }
  // eb = exp(2*(on_s @ W2^T + b2))
  float ac[16];
  #pragma unroll
  for(int r=0;r<16;r++) ac[r]=0.f;
  for(int k8=0;k8<32;k8++){
    int k2=4*k8;
    uint32 w0=wp2[(size_t)(k2+0)*H2+tid], w1=wp2[(size_t)(k2+1)*H2+tid];
    uint32 w2=wp2[(size_t)(k2+2)*H2+tid], w3=wp2[(size_t)(k2+3)*H2+tid];
    #pragma unroll
    for(int r=0;r<16;r++){
      uint4 u = *(const uint4*)&t2p[r][k2];
      ac[r]=dot2(u.x,w0,ac[r]); ac[r]=dot2(u.y,w1,ac[r]);
      ac[r]=dot2(u.z,w2,ac[r]); ac[r]=dot2(u.w,w3,ac[r]);
    }
  }
  float bb=b2[tid];
  #pragma unroll
  for(int r=0;r<16;r++) ebg[(row0+r)*H2+tid]=__expf(2.0f*(ac[r]+bb));
}

// ---------- eq = exp(2*(concat(h0,h1)@W1T+b1)) via f16 dot2, b128 LDS ----------
__global__ __launch_bounds__(256) void qp_all_k(
  const uint32* __restrict__ h16, const uint32* __restrict__ wp1, const float* __restrict__ b1,
  float* __restrict__ eqg)
{
  int m0 = blockIdx.x*16; int b = m0>>7; int t0 = m0&127;
  __shared__ __align__(16) uint32 tile[16][128];
  int tid=threadIdx.x;
  for (int i=tid;i<16*128;i+=256){
    int r=i>>7, c=i&127; int dd=c>>6, kk2=c&63;
    tile[r][c] = h16[(((size_t)(t0+r)*2 + dd)*B + b)*64 + kk2];
  }
  __syncthreads();
  float ac[16];
  #pragma unroll
  for(int r=0;r<16;r++) ac[r]=0.f;
  for(int k8=0;k8<32;k8++){
    int k2=4*k8;
    uint32 w0=wp1[(size_t)(k2+0)*H2+tid], w1=wp1[(size_t)(k2+1)*H2+tid];
    uint32 w2=wp1[(size_t)(k2+2)*H2+tid], w3=wp1[(size_t)(k2+3)*H2+tid];
    #pragma unroll
    for(int r=0;r<16;r++){
      uint4 u = *(const uint4*)&tile[r][k2];
      ac[r]=dot2(u.x,w0,ac[r]); ac[r]=dot2(u.y,w1,ac[r]);
      ac[r]=dot2(u.z,w2,ac[r]); ac[r]=dot2(u.w,w3,ac[r]);
    }
  }
  float bb=b1[tid];
  #pragma unroll
  for(int r=0;r<16;r++) eqg[(size_t)(m0+r)*H2+tid]=__expf(2.0f*(ac[r]+bb));
}

// ---------- scores: block=(b,t-half), TQ=2, eb in 32 regs; writes normalized f16 weights ----------
__global__ __launch_bounds__(512,2) void score_k(
  const float* __restrict__ eqg, const float* __restrict__ ebg,
  const float* __restrict__ att_v, uint32* __restrict__ sc16)
{
  int b  = blockIdx.x >> 1;
  int t0 = (blockIdx.x & 1) * 64;
  int tid = threadIdx.x;
  int jq = tid & 15, ttb = tid >> 4;
  __shared__ __align__(16) float eqs[2][2*H2];
  __shared__ __align__(16) float scl[2][2][T];
  __shared__ float wsum4[2][4];
  __shared__ float wvs[H2];
  uint32 ebp01[16], ebp23[16];
  float vsum_mine = 0.f;
  {
    const float* ebb = ebg + (size_t)b*T*H2;
    #pragma unroll
    for (int ii=0;ii<16;ii++){
      int j = jq + 16*ii;
      ebp01[ii] = pk_bf16(ebb[(size_t)(ttb    )*H2 + j], ebb[(size_t)(ttb+32)*H2 + j]);
      ebp23[ii] = pk_bf16(ebb[(size_t)(ttb+64 )*H2 + j], ebb[(size_t)(ttb+96)*H2 + j]);
      vsum_mine += att_v[j];
    }
  }
  if (tid < H2) wvs[tid] = -2.0f*att_v[tid];
  if (tid < 128) ((float4*)eqs[0])[tid] = ((const float4*)(eqg + ((size_t)b*T + t0)*H2))[tid];
  __syncthreads();
  int buf = 0;
  for (int tq=0; tq<64; tq+=2){
    int cur = (tq>>1)&1;
    if (tq+2 < 64 && tid < 128)
      ((float4*)eqs[buf^1])[tid] = ((const float4*)(eqg + ((size_t)b*T + t0+tq+2)*H2))[tid];
    const float* eq0 = eqs[buf];
    const float* eq1 = eqs[buf] + H2;
    float a00=vsum_mine,a01=vsum_mine,a02=vsum_mine,a03=vsum_mine;
    float a10=vsum_mine,a11=vsum_mine,a12=vsum_mine,a13=vsum_mine;
    #pragma unroll
    for (int ii=0; ii<16; ii++){
      float e0=bflo(ebp01[ii]), e1=bfhi(ebp01[ii]);
      float e2=bflo(ebp23[ii]), e3=bfhi(ebp23[ii]);
      float q0=eq0[jq+16*ii], q1=eq1[jq+16*ii];
      float w=wvs[jq+16*ii];
      a00 = fmaf(w, fast_rcp(fmaf(e0,q0,1.f)), a00);
      a01 = fmaf(w, fast_rcp(fmaf(e1,q0,1.f)), a01);
      a02 = fmaf(w, fast_rcp(fmaf(e2,q0,1.f)), a02);
      a03 = fmaf(w, fast_rcp(fmaf(e3,q0,1.f)), a03);
      a10 = fmaf(w, fast_rcp(fmaf(e0,q1,1.f)), a10);
      a11 = fmaf(w, fast_rcp(fmaf(e1,q1,1.f)), a11);
      a12 = fmaf(w, fast_rcp(fmaf(e2,q1,1.f)), a12);
      a13 = fmaf(w, fast_rcp(fmaf(e3,q1,1.f)), a13);
    }
    #pragma unroll
    for (int off=1; off<16; off<<=1){
      a00 += __shfl_xor(a00,off); a01 += __shfl_xor(a01,off);
      a02 += __shfl_xor(a02,off); a03 += __shfl_xor(a03,off);
      a10 += __shfl_xor(a10,off); a11 += __shfl_xor(a11,off);
      a12 += __shfl_xor(a12,off); a13 += __shfl_xor(a13,off);
    }
    if (jq==0){
      scl[cur][0][ttb]=__expf(a00); scl[cur][0][ttb+32]=__expf(a01);
      scl[cur][0][ttb+64]=__expf(a02); scl[cur][0][ttb+96]=__expf(a03);
      scl[cur][1][ttb]=__expf(a10); scl[cur][1][ttb+32]=__expf(a11);
      scl[cur][1][ttb+64]=__expf(a12); scl[cur][1][ttb+96]=__expf(a13);
    }
    __syncthreads();                          // A: scl[cur] ready
    if (tid < 256){
      int row = tid>>7;
      float e = scl[cur][row][tid&127];
      #pragma unroll
      for (int off=1; off<64; off<<=1) e += __shfl_xor(e,off);
      if ((tid&63)==0) wsum4[cur][tid>>6]=e;
    }
    __syncthreads();                          // B: wsum ready
    if (tid < 128){
      int row = tid>>6, i = tid&63;
      float tot = wsum4[cur][row*2] + wsum4[cur][row*2+1];
      float inv = fast_rcp(tot*128.0f);
      sc16[((size_t)b*T + t0+tq+row)*64 + i] =
        pk_f16(scl[cur][row][2*i]*inv, scl[cur][row][2*i+1]*inv);
    }
    buf ^= 1;
  }
}

// ---------- PV: ctx16 = sc16 . on_s (f16 dot2, V column in 64 regs; f16-pair output) ----------
__global__ __launch_bounds__(256,4) void pv_k(
  const uint32* __restrict__ sc16, const uint32* __restrict__ onsT, uint32* __restrict__ ctx16)
{
  int b  = blockIdx.x >> 3;
  int t0 = (blockIdx.x & 7) * 16;
  int tid = threadIdx.x;                 // output column j
  __shared__ uint32 scs[16][64];
  uint4 vreg[16];
  {
    const uint4* vp = (const uint4*)(onsT + ((size_t)b*H2 + tid)*64);
    #pragma unroll
    for (int k=0;k<16;k++) vreg[k] = vp[k];
  }
  for (int i=tid;i<1024;i+=256) ((uint32*)scs)[i] = sc16[((size_t)b*T + t0)*64 + i];
  __syncthreads();
  for (int qt=0; qt<16; qt++){
    float a0=0.f,a1=0.f,a2=0.f,a3=0.f;
    #pragma unroll
    for (int k=0;k<16;k++){
      a0 = dot2(scs[qt][4*k+0], vreg[k].x, a0);
      a1 = dot2(scs[qt][4*k+1], vreg[k].y, a1);
      a2 = dot2(scs[qt][4*k+2], vreg[k].z, a2);
      a3 = dot2(scs[qt][4*k+3], vreg[k].w, a3);
    }
    float mine = (a0+a1)+(a2+a3);
    float nb = __shfl_xor(mine, 1);
    if ((tid&1)==0)
      ctx16[((size_t)b*T + t0+qt)*128 + (tid>>1)] = pk_f16(mine, nb);
  }
}

// ---------- output projection via f16 dot2 ----------
__global__ __launch_bounds__(256) void outproj_k(
  const uint32* __restrict__ h16, const uint32* __restrict__ ctx16,
  const uint32* __restrict__ wpout, const float* __restrict__ bout, float* __restrict__ out)
{
  int m0 = blockIdx.x*16; int b = m0>>7; int t0 = m0&127;
  __shared__ __align__(16) uint32 rb[16][256];
  int tid=threadIdx.x;
  for (int i=tid;i<16*256;i+=256){
    int r=i>>8, c=i&255;
    int t = t0+r;
    uint32 v;
    if (c<64)        v = h16[(((size_t)(t+1)*2 + 0)*B + b)*64 + c];
    else if (c<128)  v = h16[(((size_t)(t+1)*2 + 1)*B + b)*64 + (c-64)];
    else             v = ctx16[((size_t)(m0+r))*128 + (c-128)];
    rb[r][c]=v;
  }
  __syncthreads();
  for (int o=tid;o<16*D;o+=256){
    int r=o/D, j=o-r*D;
    float acc=bout[j];
    for (int k4=0;k4<64;k4++){
      uint4 u = *(const uint4*)&rb[r][4*k4];
      acc = dot2(u.x, wpout[(size_t)(4*k4+0)*D+j], acc);
      acc = dot2(u.y, wpout[(size_t)(4*k4+1)*D+j], acc);
      acc = dot2(u.z, wpout[(size_t)(4*k4+2)*D+j], acc);
      acc = dot2(u.w, wpout[(size_t)(4*k4+3)*D+j], acc);
    }
    out[((size_t)(m0+r))*D + j]=acc;
  }
}

extern "C" void kernel_launch(void* const* d_in, const int* in_sizes, int n_in,
                              void* d_out, int out_size, void* d_ws, size_t ws_size,
                              hipStream_t stream) {
  const float* x      =(const float*)d_in[0];
  const float* eps_z  =(const float*)d_in[1];
  const float* eps_on =(const float*)d_in[2];
  const float* enc_Wih=(const float*)d_in[3];
  const float* enc_Whh=(const float*)d_in[4];
  const float* enc_b  =(const float*)d_in[5];
  const float* dec_Wih=(const float*)d_in[6];
  const float* dec_Whh=(const float*)d_in[7];
  const float* dec_b  =(const float*)d_in[8];
  const float* Wzmu=(const float*)d_in[9];  const float* bzmu=(const float*)d_in[10];
  const float* Wzlv=(const float*)d_in[11]; const float* bzlv=(const float*)d_in[12];
  const float* Womu=(const float*)d_in[13]; const float* bomu=(const float*)d_in[14];
  const float* Wolv=(const float*)d_in[15]; const float* bolv=(const float*)d_in[16];
  const float* att_v=(const float*)d_in[17];
  const float* att_W1=(const float*)d_in[18]; const float* att_b1=(const float*)d_in[19];
  const float* att_W2=(const float*)d_in[20]; const float* att_b2=(const float*)d_in[21];
  const float* Wout=(const float*)d_in[22];  const float* bout=(const float*)d_in[23];
  float* out=(float*)d_out;
  float* ws=(float*)d_ws;
  (void)ws_size; (void)n_in; (void)in_sizes; (void)out_size;

  size_t o=0;
  float* WzmuT=ws+o; o+=H*H;
  float* WzlvT=ws+o; o+=H*H;
  uint32* wpkE=(uint32*)(ws+o); o+=65536;
  uint32* wpkD=(uint32*)(ws+o); o+=65536;
  uint32* wpmu=(uint32*)(ws+o); o+=32768;   // [k2=128][256]
  uint32* wplv=(uint32*)(ws+o); o+=32768;
  uint32* wp1 =(uint32*)(ws+o); o+=32768;
  uint32* wp2 =(uint32*)(ws+o); o+=32768;
  uint32* wpout=(uint32*)(ws+o); o+=19456;  // [k2=256][76]
  uint32* wxE =(uint32*)(ws+o); o+=38912;   // [d][k2=38][512]
  uint32* wxD =(uint32*)(ws+o); o+=38912;
  float* h_fin=ws+o; o+=2*B*H;
  __half* on16=(__half*)(ws+o); o+=(size_t)B*T*H2/2;
  uint32* h16 =(uint32*)(ws+o); o+=(size_t)(T+1)*2*B*64;   // f16 pairs [t][d][b][h/2]
  float* Abase=ws+o; o+=16777216;                // 64MB: xgh -> {eqg 32MB | ctx16 16MB}
  float* Cbase=ws+o; o+=14680064;                // 56MB: onsT 16MB + ebg 32MB + sc16 8MB

  __half* xgh = (__half*)Abase;
  float* eqg  = Abase;
  uint32* ctx16 = (uint32*)(Abase + 8388608);
  uint32* onsT = (uint32*)Cbase;
  float* ebg  = Cbase + 4194304;
  uint32* sc16 = (uint32*)(Cbase + 4194304 + 8388608);

  PrepArgs pa;
  {
    const float* srcs[2]={Wzmu,Wzlv};
    float* dsts[2]={WzmuT,WzlvT};
    for(int i=0;i<2;i++){pa.src[i]=srcs[i];pa.dst[i]=dsts[i];pa.R[i]=H;pa.C[i]=H;}
  }
  Pack2Args p2;
  {
    const float* srcs[9]={Womu,Wolv,att_W1,att_W2,Wout,
                          enc_Wih, enc_Wih + (size_t)512*76,
                          dec_Wih, dec_Wih + (size_t)512*76};
    uint32* dsts[9]={wpmu,wplv,wp1,wp2,wpout, wxE, wxE+19456, wxD, wxD+19456};
    int Ns[9]={H2,H2,H2,H2,D, 512,512,512,512};
    int Ks[9]={H2,H2,H2,H2,G, D,D,D,D};
    for(int i=0;i<9;i++){p2.src[i]=srcs[i];p2.dst[i]=dsts[i];p2.N[i]=Ns[i];p2.K[i]=Ks[i];}
  }
  prep_k<<<64,256,0,stream>>>(pa);
  pack2_k<<<288,256,0,stream>>>(p2);
  pack_whh_k<<<512,256,0,stream>>>(enc_Whh, dec_Whh, wpkE, wpkD);

  // encoder phase
  xg_k<<<4096,256,0,stream>>>(x, wxE, enc_b, xgh, 0);
  rec_k<1><<<512,512,0,stream>>>(xgh, wpkE, nullptr, on16, h_fin, nullptr);
  z_k<<<512,128,0,stream>>>(h_fin, WzmuT,bzmu,WzlvT,bzlv,eps_z, h16);
  onsw2v_k<<<2048,256,0,stream>>>((const uint32*)on16,wpmu,bomu,wplv,bolv,eps_on,wp2,att_b2,onsT,ebg);

  // decoder phase (xgh reuses region A; eqg overwrites it after rec_k<0>)
  xg_k<<<4096,256,0,stream>>>(x, wxD, dec_b, xgh, 1);
  rec_k<0><<<512,512,0,stream>>>(xgh, wpkD, (const __half*)h16, nullptr, nullptr, h16);

  qp_all_k<<<2048,256,0,stream>>>(h16, wp1, att_b1, eqg);
  score_k<<<512,512,0,stream>>>(eqg, ebg, att_v, sc16);
  pv_k<<<2048,256,0,stream>>>(sc16, onsT, ctx16);
  outproj_k<<<2048,256,0,stream>>>(h16, ctx16, wpout, bout, out);
}